// Round 18
// baseline (156.080 us; speedup 1.0000x reference)
//
#include <hip/hip_runtime.h>
#include <hip/hip_fp16.h>
#include <math.h>

#define NN 100000
#define NE 1600000

#define BSH  9          // bucket = dst >> 9
#define BKN  512        // nodes per bucket
#define NB   196        // ceil(NN/512)
#define ABLK 128        // partition blocks  (EPB/NB ~ 64-entry runs = 256B, WC-safe)
#define EPB  ((NE + ABLK - 1) / ABLK)   // 12500 edges per partition block
#define GEMMB ((NN + 63) / 64)          // 1563 gemm tiles
#define GBLK ((GEMMB + 1) / 2)          // 782 gemm blocks (2 tiles each)
#define LDST 136

typedef __attribute__((ext_vector_type(8))) short bf16x8;
typedef __attribute__((ext_vector_type(4))) float f32x4;

__device__ __forceinline__ unsigned short f2bf(float f) {
    unsigned u = __builtin_bit_cast(unsigned, f);
    u += 0x7fffu + ((u >> 16) & 1u);           // RNE
    return (unsigned short)(u >> 16);
}
__device__ __forceinline__ float bf2f(unsigned short h) {
    unsigned u = ((unsigned)h) << 16;
    return __builtin_bit_cast(float, u);
}
__device__ __forceinline__ float2 unpackh2(unsigned w) {
    const __half2 h = __builtin_bit_cast(__half2, w);
    return __half22float2(h);
}

struct GemmSmem { unsigned short sAh[64 * LDST]; unsigned short sAl[64 * LDST]; };
struct PartSmem { int h[BKN]; int cur[BKN]; int wsum[8]; };
union FusedSmem { GemmSmem gm; PartSmem pb; };

// ============ K1: fused count (blocks 0..127) + precomp (128..256) ============
__global__ __launch_bounds__(256) void fused0(const int* __restrict__ dst,
    const float* __restrict__ w1l, const float* __restrict__ w1r,
    const float* __restrict__ w2l, const float* __restrict__ w2r,
    const float* __restrict__ b1, const float* __restrict__ fc1w,
    const float* __restrict__ fc1b, const float* __restrict__ fc2w,
    const float* __restrict__ fc2b, int* __restrict__ mat,
    unsigned short* __restrict__ ATh, unsigned short* __restrict__ ATl,
    float* __restrict__ cbuf)
{
    __shared__ int h[NB];
    __shared__ float sl[64], sr[64];
    const int t = threadIdx.x;
    if (blockIdx.x < ABLK) {
        for (int i = t; i < NB; i += 256) h[i] = 0;
        __syncthreads();
        const int a = blockIdx.x;
        const int beg = a * EPB;
        const int end = (beg + EPB < NE) ? beg + EPB : NE;
        for (int e = beg + t; e < end; e += 256)
            atomicAdd(&h[dst[e] >> BSH], 1);
        __syncthreads();
        for (int i = t; i < NB; i += 256) mat[(size_t)i * ABLK + a] = h[i];
        return;
    }
    if (blockIdx.x < ABLK + 128) {
        const int k = blockIdx.x - ABLK;
        const int j = t;
        if (j < 64) { sl[j] = w1l[k * 64 + j]; sr[j] = w1r[k * 64 + j]; }
        __syncthreads();
        if (j < 64) {
            const int sel = j >> 4, jj = j & 15;
            const float* row = (sel < 2) ? sl : sr;
            const float* w2  = (sel & 1) ? w2r : w2l;
            float acc = 0.f;
#pragma unroll
            for (int m = 0; m < 64; ++m) acc = fmaf(row[m], w2[m * 16 + jj], acc);
            const unsigned short hh = f2bf(acc);
            ATh[j * 128 + k] = hh;                  // transposed: [col][k]
            ATl[j * 128 + k] = f2bf(acc - bf2f(hh));
        }
        return;
    }
    const int j = t;
    if (j < 16) {
        float a = 0.f;
        for (int m = 0; m < 64; ++m) a = fmaf(b1[m], w2l[m * 16 + j], a);
        cbuf[j] = a;
    } else if (j < 32) {
        const int jj = j - 16;
        float a = 0.f;
        for (int m = 0; m < 64; ++m) a = fmaf(b1[m], w2r[m * 16 + jj], a);
        cbuf[j] = a;
    } else if (j < 48) {
        const int k = j - 32;
        float a = 0.f;
        for (int m = 0; m < 8; ++m) a = fmaf(fc1w[k * 8 + m], fc2w[m], a);
        cbuf[j] = a;
    } else if (j == 48) {
        float a = fc2b[0];
        for (int m = 0; m < 8; ++m) a = fmaf(fc1b[m], fc2w[m], a);
        cbuf[48] = a;
    }
}

// single 256-thread block: per-bucket prefix over ABLK + block-scan of totals
__global__ __launch_bounds__(256) void scan_all(int* __restrict__ mat,
    int* __restrict__ bbase)
{
    __shared__ int s[256];
    const int t = threadIdx.x;
    int run = 0;
    if (t < NB) {
        int* col = mat + (size_t)t * ABLK;
        for (int a = 0; a < ABLK; ++a) { const int v = col[a]; col[a] = run; run += v; }
    }
    s[t] = (t < NB) ? run : 0;
    __syncthreads();
    for (int off = 1; off < 256; off <<= 1) {
        const int u = (t >= off) ? s[t - off] : 0;
        __syncthreads();
        s[t] += u;
        __syncthreads();
    }
    if (t < NB) bbase[t] = s[t] - run;         // exclusive
    if (t == NB - 1) bbase[NB] = s[t];         // == NE
}

// ============ K3: scatter (solo, 512 threads) ============
__global__ __launch_bounds__(512) void partA_scatter(const int* __restrict__ src,
    const int* __restrict__ dst, const int* __restrict__ mat,
    const int* __restrict__ bbase, unsigned* __restrict__ part)
{
    __shared__ int cur[NB];
    const int a = blockIdx.x;
    for (int i = threadIdx.x; i < NB; i += 512)
        cur[i] = mat[(size_t)i * ABLK + a] + bbase[i];
    __syncthreads();
    const int beg = a * EPB;
    const int end = (beg + EPB < NE) ? beg + EPB : NE;
    for (int e = beg + threadIdx.x; e < end; e += 512) {
        const int s = src[e], d = dst[e];
        const int pos = atomicAdd(&cur[d >> BSH], 1);
        part[pos] = ((unsigned)s << BSH) | (unsigned)(d & (BKN - 1));
    }
}

// ============ K4: fused partB (blocks 0..NB-1) + MFMA gemm (NB..) ============
__global__ __launch_bounds__(512) void fused2(const unsigned* __restrict__ part,
    const int* __restrict__ bbase, int* __restrict__ rowptr, int* __restrict__ cols,
    const float* __restrict__ x, const unsigned short* __restrict__ ATh,
    const unsigned short* __restrict__ ATl, signed char* __restrict__ p8,
    float* __restrict__ pscale, __half* __restrict__ qh)
{
    __shared__ FusedSmem su;
    const int tid = threadIdx.x;

    if (blockIdx.x < NB) {
        // ---- partB_build ----
        int* h = su.pb.h;
        int* cur = su.pb.cur;
        int* wsum = su.pb.wsum;
        const int b = blockIdx.x;
        const int t = tid;
        const int beg = bbase[b], end = bbase[b + 1];
        h[t] = 0;
        __syncthreads();
        for (int e = beg + t; e < end; e += 512)
            atomicAdd(&h[part[e] & (BKN - 1u)], 1);
        __syncthreads();
        const int v = h[t];
        int inc = v;
#pragma unroll
        for (int d = 1; d < 64; d <<= 1) {
            const int u = __shfl_up(inc, d, 64);
            if ((t & 63) >= d) inc += u;
        }
        if ((t & 63) == 63) wsum[t >> 6] = inc;
        __syncthreads();
        int woff = 0;
        for (int w = 0; w < (t >> 6); ++w) woff += wsum[w];
        const int excl = inc + woff - v;
        cur[t] = excl;
        const int node = b * BKN + t;
        if (node < NN) rowptr[node] = beg + excl;
        if (b == NB - 1 && t == 0) rowptr[NN] = NE;
        __syncthreads();
        for (int e = beg + t; e < end; e += 512) {
            const unsigned w = part[e];
            const int pos = atomicAdd(&cur[w & (BKN - 1u)], 1);
            cols[beg + pos] = (int)(w >> BSH);
        }
        return;
    }

    // ---- gemm: 2 tiles per block, shared A staging ----
    unsigned short* sAh = su.gm.sAh;
    unsigned short* sAl = su.gm.sAl;
    for (int i = tid; i < 1024; i += 512) {
        const int row = i >> 4, ch = i & 15;
        const uint4 vh = *(const uint4*)(ATh + row * 128 + ch * 8);
        const uint4 vl = *(const uint4*)(ATl + row * 128 + ch * 8);
        *(uint4*)(sAh + row * LDST + ch * 8) = vh;
        *(uint4*)(sAl + row * LDST + ch * 8) = vl;
    }
    __syncthreads();

    const int wave8 = tid >> 6;            // 0..7
    const int tile = (blockIdx.x - NB) * 2 + (wave8 >> 2);
    const int wave = wave8 & 3;            // 0..3 within tile-group
    const int lane = tid & 63;
    const int lr = lane & 15;
    const int lg = lane >> 4;

    bf16x8 bh[4][4], bl[4][4];
#pragma unroll
    for (int ct = 0; ct < 4; ++ct) {
        const int col = ct * 16 + lr;
#pragma unroll
        for (int ks = 0; ks < 4; ++ks) {
            const int k0 = ks * 32 + lg * 8;
            bh[ct][ks] = *(const bf16x8*)(sAh + col * LDST + k0);
            bl[ct][ks] = *(const bf16x8*)(sAl + col * LDST + k0);
        }
    }

    if (tile >= GEMMB) return;
    const int tilebase = tile * 64;
    const int xrowidx = tilebase + wave * 16 + lr;
    const float* xrow = x + (size_t)(xrowidx < NN ? xrowidx : NN - 1) * 128;

    f32x4 acc[4] = {f32x4{0,0,0,0}, f32x4{0,0,0,0}, f32x4{0,0,0,0}, f32x4{0,0,0,0}};
#pragma unroll
    for (int ks = 0; ks < 4; ++ks) {
        const int k0 = ks * 32 + lg * 8;
        const float4 v0 = *(const float4*)(xrow + k0);
        const float4 v1 = *(const float4*)(xrow + k0 + 4);
        const float vv[8] = {v0.x, v0.y, v0.z, v0.w, v1.x, v1.y, v1.z, v1.w};
        bf16x8 xh, xl;
#pragma unroll
        for (int j = 0; j < 8; ++j) {
            const unsigned short h = f2bf(vv[j]);
            xh[j] = (short)h;
            xl[j] = (short)f2bf(vv[j] - bf2f(h));
        }
#pragma unroll
        for (int ct = 0; ct < 4; ++ct) {
            acc[ct] = __builtin_amdgcn_mfma_f32_16x16x32_bf16(xh, bh[ct][ks], acc[ct], 0, 0, 0);
            acc[ct] = __builtin_amdgcn_mfma_f32_16x16x32_bf16(xh, bl[ct][ks], acc[ct], 0, 0, 0);
            acc[ct] = __builtin_amdgcn_mfma_f32_16x16x32_bf16(xl, bh[ct][ks], acc[ct], 0, 0, 0);
        }
    }

#pragma unroll
    for (int rg = 0; rg < 4; ++rg) {
        float m = fmaxf(fabsf(acc[0][rg]), fabsf(acc[1][rg]));
#pragma unroll
        for (int d = 1; d < 16; d <<= 1) m = fmaxf(m, __shfl_xor(m, d, 64));
        m = fmaxf(m, 1e-20f);
        const float scl = m * (1.0f / 127.0f);
        const float inv = 127.0f / m;
        const int nrow = tilebase + wave * 16 + lg * 4 + rg;
        if (nrow < NN) {
            const int q0 = __float2int_rn(acc[0][rg] * inv);
            const int q1 = __float2int_rn(acc[1][rg] * inv);
            p8[(size_t)nrow * 32 + lr]      = (signed char)q0;
            p8[(size_t)nrow * 32 + 16 + lr] = (signed char)q1;
            if (lr == 0) pscale[nrow] = scl;
            qh[(size_t)nrow * 32 + lr]      = __float2half(acc[2][rg]);
            qh[(size_t)nrow * 32 + 16 + lr] = __float2half(acc[3][rg]);
        }
    }
}

// ============ aggregation via CSR (16 edge-slots x uint4 loads) ============
// layer 1: 32 lanes per node = 16 edge-slots x 2 lanes; lane k loads uint4
// (16 int8 feats). 16 edges in flight per node, half the VMEM instructions.
__global__ __launch_bounds__(256) void agg1_csr(const int* __restrict__ rowptr,
    const int* __restrict__ cols, const signed char* __restrict__ p8,
    const float* __restrict__ pscale, const __half* __restrict__ qh,
    const float* __restrict__ cbuf, __half* __restrict__ g, __half* __restrict__ r)
{
    const int node = blockIdx.x * 8 + (threadIdx.x >> 5);
    if (node >= NN) return;
    const int lane = threadIdx.x & 31;
    const int es = lane >> 1;      // edge slot 0..15
    const int k  = lane & 1;       // uint4 index: feats 16k..16k+15
    const int beg = rowptr[node], end = rowptr[node + 1];
    const uint4* p128 = (const uint4*)p8;
    float a[16];
#pragma unroll
    for (int i = 0; i < 16; ++i) a[i] = 0.f;
    for (int j = beg; j < end; j += 16) {
        const int jj = j + es;
        const int s = cols[(jj < end) ? jj : (end - 1)];
        const float scl = (jj < end) ? pscale[s] : 0.f;
        const uint4 w = p128[(size_t)s * 2 + k];
        const unsigned ws[4] = {w.x, w.y, w.z, w.w};
#pragma unroll
        for (int q = 0; q < 4; ++q) {
            a[q * 4 + 0] = fmaf((float)(signed char)(ws[q] & 0xffu), scl, a[q * 4 + 0]);
            a[q * 4 + 1] = fmaf((float)(signed char)((ws[q] >> 8) & 0xffu), scl, a[q * 4 + 1]);
            a[q * 4 + 2] = fmaf((float)(signed char)((ws[q] >> 16) & 0xffu), scl, a[q * 4 + 2]);
            a[q * 4 + 3] = fmaf((float)(signed char)(ws[q] >> 24), scl, a[q * 4 + 3]);
        }
    }
#pragma unroll
    for (int d = 2; d <= 16; d <<= 1) {
#pragma unroll
        for (int i = 0; i < 16; ++i) a[i] += __shfl_xor(a[i], d, 64);
    }
    if (es == 0) {
        // lane k holds feats 16k..16k+15
        const float dg = (float)(end - beg);
        const float inv = 1.0f / fmaxf(dg, 1.0f);
        const uint4 qw0 = *(const uint4*)(qh + (size_t)node * 32 + 16 * k);
        const uint4 qw1 = *(const uint4*)(qh + (size_t)node * 32 + 16 * k + 8);
        const unsigned qws[8] = {qw0.x, qw0.y, qw0.z, qw0.w, qw1.x, qw1.y, qw1.z, qw1.w};
        float val[16];
#pragma unroll
        for (int i = 0; i < 16; ++i) {
            const float2 qq = unpackh2(qws[i >> 1]);
            const float qv = (i & 1) ? qq.y : qq.x;
            val[i] = fmaf(a[i], inv, qv + cbuf[16 * k + i]);
        }
        unsigned ow[8];
#pragma unroll
        for (int i = 0; i < 8; ++i)
            ow[i] = __builtin_bit_cast(unsigned, __floats2half2_rn(val[2 * i], val[2 * i + 1]));
        __half* dptr = (k == 0) ? (g + (size_t)node * 16) : (r + (size_t)node * 16);
        *(uint4*)(dptr)     = make_uint4(ow[0], ow[1], ow[2], ow[3]);
        *(uint4*)(dptr + 8) = make_uint4(ow[4], ow[5], ow[6], ow[7]);
    }
}

// layer 2: 32 lanes per node = 16 edge-slots x 2 lanes; lane k loads uint4
// (8 fp16 feats: feats 8k..8k+7).
__global__ __launch_bounds__(256) void agg2_csr(const int* __restrict__ rowptr,
    const int* __restrict__ cols, const __half* __restrict__ g,
    const __half* __restrict__ r, const float* __restrict__ b2,
    __half* __restrict__ h2)
{
    const int node = blockIdx.x * 8 + (threadIdx.x >> 5);
    if (node >= NN) return;
    const int lane = threadIdx.x & 31;
    const int es = lane >> 1;      // 0..15
    const int k  = lane & 1;       // feats 8k..8k+7
    const int beg = rowptr[node], end = rowptr[node + 1];
    const uint4* g128 = (const uint4*)g;
    float a[8];
#pragma unroll
    for (int i = 0; i < 8; ++i) a[i] = 0.f;
    for (int j = beg; j < end; j += 16) {
        const int jj = j + es;
        const int s = cols[(jj < end) ? jj : (end - 1)];
        const float m = (jj < end) ? 1.0f : 0.0f;
        const uint4 w = g128[(size_t)s * 2 + k];
        const unsigned ws[4] = {w.x, w.y, w.z, w.w};
#pragma unroll
        for (int q = 0; q < 4; ++q) {
            const float2 v = unpackh2(ws[q]);
            a[q * 2 + 0] = fmaf(v.x, m, a[q * 2 + 0]);
            a[q * 2 + 1] = fmaf(v.y, m, a[q * 2 + 1]);
        }
    }
#pragma unroll
    for (int d = 2; d <= 16; d <<= 1) {
#pragma unroll
        for (int i = 0; i < 8; ++i) a[i] += __shfl_xor(a[i], d, 64);
    }
    if (es == 0) {
        const float dg = (float)(end - beg);
        const float inv = 1.0f / fmaxf(dg, 1.0f);
        const uint4 rw = *(const uint4*)(r + (size_t)node * 16 + 8 * k);
        const unsigned rws[4] = {rw.x, rw.y, rw.z, rw.w};
        unsigned ow[4];
#pragma unroll
        for (int q = 0; q < 4; ++q) {
            const float2 rv = unpackh2(rws[q]);
            const float v0 = fmaf(a[q * 2 + 0], inv, rv.x + b2[8 * k + q * 2 + 0]);
            const float v1 = fmaf(a[q * 2 + 1], inv, rv.y + b2[8 * k + q * 2 + 1]);
            ow[q] = __builtin_bit_cast(unsigned, __floats2half2_rn(v0, v1));
        }
        *(uint4*)(h2 + (size_t)node * 16 + 8 * k) = make_uint4(ow[0], ow[1], ow[2], ow[3]);
    }
}

// ---- out = sigmoid( sum_k h2[s][k]*h2[d][k]*v[k] + c ); 2 edges per thread
__global__ __launch_bounds__(256) void edge_mlp(const int* __restrict__ src,
    const int* __restrict__ dst, const __half* __restrict__ h2,
    const float* __restrict__ cbuf, float* __restrict__ out)
{
    __shared__ float sv[17];
    if (threadIdx.x < 16) sv[threadIdx.x] = cbuf[32 + threadIdx.x];
    if (threadIdx.x == 16) sv[16] = cbuf[48];
    __syncthreads();
    const int e0 = blockIdx.x * 512 + threadIdx.x;
    const int e1 = e0 + 256;            // NE % 512 == 0 -> both valid
    const int s0 = src[e0], d0 = dst[e0];
    const int s1 = src[e1], d1 = dst[e1];
    const uint4* hs0 = (const uint4*)(h2 + (size_t)s0 * 16);
    const uint4* hd0 = (const uint4*)(h2 + (size_t)d0 * 16);
    const uint4* hs1 = (const uint4*)(h2 + (size_t)s1 * 16);
    const uint4* hd1 = (const uint4*)(h2 + (size_t)d1 * 16);
    const uint4 a00 = hs0[0], a01 = hs0[1];
    const uint4 b00 = hd0[0], b01 = hd0[1];
    const uint4 a10 = hs1[0], a11 = hs1[1];
    const uint4 b10 = hd1[0], b11 = hd1[1];
    const unsigned aw0[8] = {a00.x, a00.y, a00.z, a00.w, a01.x, a01.y, a01.z, a01.w};
    const unsigned bw0[8] = {b00.x, b00.y, b00.z, b00.w, b01.x, b01.y, b01.z, b01.w};
    const unsigned aw1[8] = {a10.x, a10.y, a10.z, a10.w, a11.x, a11.y, a11.z, a11.w};
    const unsigned bw1[8] = {b10.x, b10.y, b10.z, b10.w, b11.x, b11.y, b11.z, b11.w};
    float acc0 = sv[16], acc1 = sv[16];
#pragma unroll
    for (int qq = 0; qq < 8; ++qq) {
        const float2 a0 = unpackh2(aw0[qq]), b0 = unpackh2(bw0[qq]);
        const float2 a1 = unpackh2(aw1[qq]), b1 = unpackh2(bw1[qq]);
        acc0 = fmaf(a0.x * b0.x, sv[qq * 2 + 0], acc0);
        acc0 = fmaf(a0.y * b0.y, sv[qq * 2 + 1], acc0);
        acc1 = fmaf(a1.x * b1.x, sv[qq * 2 + 0], acc1);
        acc1 = fmaf(a1.y * b1.y, sv[qq * 2 + 1], acc1);
    }
    out[e0] = 1.0f / (1.0f + __expf(-acc0));
    out[e1] = 1.0f / (1.0f + __expf(-acc1));
}

extern "C" void kernel_launch(void* const* d_in, const int* in_sizes, int n_in,
                              void* d_out, int out_size, void* d_ws, size_t ws_size,
                              hipStream_t stream)
{
    const float* x    = (const float*)d_in[0];
    const int*   ei   = (const int*)d_in[1];
    const float* w1l  = (const float*)d_in[2];
    const float* w1r  = (const float*)d_in[3];
    const float* b1   = (const float*)d_in[4];
    const float* w2l  = (const float*)d_in[5];
    const float* w2r  = (const float*)d_in[6];
    const float* b2   = (const float*)d_in[7];
    const float* fc1w = (const float*)d_in[8];
    const float* fc1b = (const float*)d_in[9];
    const float* fc2w = (const float*)d_in[10];
    const float* fc2b = (const float*)d_in[11];
    float* out = (float*)d_out;

    const int* src = ei;
    const int* dst = ei + NE;

    // workspace layout (int units)
    int* W = (int*)d_ws;
    size_t o = 0;
#define ALIGN16() o = (o + 15) & ~(size_t)15
    int* mat    = W + o; o += (size_t)NB * ABLK; ALIGN16();
    int* bbase  = W + o; o += NB + 1;            ALIGN16();
    int* rowptr = W + o; o += NN + 1;            ALIGN16();
    unsigned* part = (unsigned*)(W + o); o += NE; ALIGN16();
    int* cols   = W + o; o += NE;                ALIGN16();
    unsigned short* ATh = (unsigned short*)(W + o); o += 4096; ALIGN16();
    unsigned short* ATl = (unsigned short*)(W + o); o += 4096; ALIGN16();
    float* cbuf = (float*)(W + o); o += 64;      ALIGN16();
    signed char* p8 = (signed char*)(W + o); o += (size_t)NN * 8;  ALIGN16();
    float* pscale   = (float*)(W + o); o += NN;  ALIGN16();
    __half* qh  = (__half*)(W + o); o += (size_t)NN * 16; ALIGN16();
    __half* g   = (__half*)(W + o); o += (size_t)NN * 8;  ALIGN16();
    __half* r   = (__half*)(W + o); o += (size_t)NN * 8;  ALIGN16();
    __half* h2  = (__half*)(W + o); o += (size_t)NN * 8;  ALIGN16();

    // K1: count || precomp
    fused0<<<ABLK + 129, 256, 0, stream>>>(dst, w1l, w1r, w2l, w2r, b1,
                                           fc1w, fc1b, fc2w, fc2b, mat, ATh, ATl, cbuf);
    // K2: scan
    scan_all<<<1, 256, 0, stream>>>(mat, bbase);
    // K3: scatter (solo -> whole machine)
    partA_scatter<<<ABLK, 512, 0, stream>>>(src, dst, mat, bbase, part);
    // K4: partB || gemm (gemm off critical path hides under partB)
    fused2<<<NB + GBLK, 512, 0, stream>>>(part, bbase, rowptr, cols,
                                          x, ATh, ATl, p8, pscale, qh);
    // K5/K6: aggregations (uint4 gathers, half the VMEM instructions)
    agg1_csr<<<(NN + 7) / 8, 256, 0, stream>>>(rowptr, cols, p8, pscale, qh, cbuf, g, r);
    agg2_csr<<<(NN + 7) / 8, 256, 0, stream>>>(rowptr, cols, g, r, b2, h2);
    // K7: head
    edge_mlp<<<NE / 512, 256, 0, stream>>>(src, dst, h2, cbuf, out);
}

// Round 19
// 137.780 us; speedup vs baseline: 1.1328x; 1.1328x over previous
//
#include <hip/hip_runtime.h>
#include <hip/hip_fp16.h>
#include <math.h>

#define NN 100000
#define NE 1600000

#define BSH  9          // bucket = dst >> 9
#define BKN  512        // nodes per bucket
#define NB   196        // ceil(NN/512)
#define ABLK 128        // partition blocks  (EPB/NB ~ 64-entry runs = 256B, WC-safe)
#define EPB  ((NE + ABLK - 1) / ABLK)   // 12500 edges per partition block
#define GEMMB ((NN + 63) / 64)          // 1563 gemm tiles
#define GBLK ((GEMMB + 1) / 2)          // 782 gemm blocks (2 tiles each)
#define LDST 136

typedef __attribute__((ext_vector_type(8))) short bf16x8;
typedef __attribute__((ext_vector_type(4))) float f32x4;

__device__ __forceinline__ unsigned short f2bf(float f) {
    unsigned u = __builtin_bit_cast(unsigned, f);
    u += 0x7fffu + ((u >> 16) & 1u);           // RNE
    return (unsigned short)(u >> 16);
}
__device__ __forceinline__ float bf2f(unsigned short h) {
    unsigned u = ((unsigned)h) << 16;
    return __builtin_bit_cast(float, u);
}
__device__ __forceinline__ float2 unpackh2(unsigned w) {
    const __half2 h = __builtin_bit_cast(__half2, w);
    return __half22float2(h);
}

// ============ K1: fused count (blocks 0..127) + precomp (128..256) ============
__global__ __launch_bounds__(256) void fused0(const int* __restrict__ dst,
    const float* __restrict__ w1l, const float* __restrict__ w1r,
    const float* __restrict__ w2l, const float* __restrict__ w2r,
    const float* __restrict__ b1, const float* __restrict__ fc1w,
    const float* __restrict__ fc1b, const float* __restrict__ fc2w,
    const float* __restrict__ fc2b, int* __restrict__ mat,
    unsigned short* __restrict__ ATh, unsigned short* __restrict__ ATl,
    float* __restrict__ cbuf)
{
    __shared__ int h[NB];
    __shared__ float sl[64], sr[64];
    const int t = threadIdx.x;
    if (blockIdx.x < ABLK) {
        for (int i = t; i < NB; i += 256) h[i] = 0;
        __syncthreads();
        const int a = blockIdx.x;
        const int beg = a * EPB;
        const int end = (beg + EPB < NE) ? beg + EPB : NE;
        for (int e = beg + t; e < end; e += 256)
            atomicAdd(&h[dst[e] >> BSH], 1);
        __syncthreads();
        for (int i = t; i < NB; i += 256) mat[(size_t)i * ABLK + a] = h[i];
        return;
    }
    if (blockIdx.x < ABLK + 128) {
        const int k = blockIdx.x - ABLK;
        const int j = t;
        if (j < 64) { sl[j] = w1l[k * 64 + j]; sr[j] = w1r[k * 64 + j]; }
        __syncthreads();
        if (j < 64) {
            const int sel = j >> 4, jj = j & 15;
            const float* row = (sel < 2) ? sl : sr;
            const float* w2  = (sel & 1) ? w2r : w2l;
            float acc = 0.f;
#pragma unroll
            for (int m = 0; m < 64; ++m) acc = fmaf(row[m], w2[m * 16 + jj], acc);
            const unsigned short hh = f2bf(acc);
            ATh[j * 128 + k] = hh;                  // transposed: [col][k]
            ATl[j * 128 + k] = f2bf(acc - bf2f(hh));
        }
        return;
    }
    const int j = t;
    if (j < 16) {
        float a = 0.f;
        for (int m = 0; m < 64; ++m) a = fmaf(b1[m], w2l[m * 16 + j], a);
        cbuf[j] = a;
    } else if (j < 32) {
        const int jj = j - 16;
        float a = 0.f;
        for (int m = 0; m < 64; ++m) a = fmaf(b1[m], w2r[m * 16 + jj], a);
        cbuf[j] = a;
    } else if (j < 48) {
        const int k = j - 32;
        float a = 0.f;
        for (int m = 0; m < 8; ++m) a = fmaf(fc1w[k * 8 + m], fc2w[m], a);
        cbuf[j] = a;
    } else if (j == 48) {
        float a = fc2b[0];
        for (int m = 0; m < 8; ++m) a = fmaf(fc1b[m], fc2w[m], a);
        cbuf[48] = a;
    }
}

// single 256-thread block: per-bucket prefix over ABLK + block-scan of totals
__global__ __launch_bounds__(256) void scan_all(int* __restrict__ mat,
    int* __restrict__ bbase)
{
    __shared__ int s[256];
    const int t = threadIdx.x;
    int run = 0;
    if (t < NB) {
        int* col = mat + (size_t)t * ABLK;
        for (int a = 0; a < ABLK; ++a) { const int v = col[a]; col[a] = run; run += v; }
    }
    s[t] = (t < NB) ? run : 0;
    __syncthreads();
    for (int off = 1; off < 256; off <<= 1) {
        const int u = (t >= off) ? s[t - off] : 0;
        __syncthreads();
        s[t] += u;
        __syncthreads();
    }
    if (t < NB) bbase[t] = s[t] - run;         // exclusive
    if (t == NB - 1) bbase[NB] = s[t];         // == NE
}

// ============ K3: fused scatter (blocks 0..127) + MFMA gemm (128..) ============
// 512 threads: scatter gets 8-wave strides; gemm does 2 tiles/block sharing one
// LDS A-staging -> 8 waves/block x 4 blocks/CU = full wave occupancy.
__global__ __launch_bounds__(512) void fused1(const int* __restrict__ src,
    const int* __restrict__ dst, const int* __restrict__ mat,
    const int* __restrict__ bbase, unsigned* __restrict__ part,
    const float* __restrict__ x, const unsigned short* __restrict__ ATh,
    const unsigned short* __restrict__ ATl, signed char* __restrict__ p8,
    float* __restrict__ pscale, __half* __restrict__ qh)
{
    __shared__ unsigned short sAh[64 * LDST];
    __shared__ unsigned short sAl[64 * LDST];
    __shared__ int cur[NB];
    const int tid = threadIdx.x;

    if (blockIdx.x < ABLK) {
        // ---- partA_scatter ----
        const int a = blockIdx.x;
        for (int i = tid; i < NB; i += 512)
            cur[i] = mat[(size_t)i * ABLK + a] + bbase[i];
        __syncthreads();
        const int beg = a * EPB;
        const int end = (beg + EPB < NE) ? beg + EPB : NE;
        for (int e = beg + tid; e < end; e += 512) {
            const int s = src[e], d = dst[e];
            const int pos = atomicAdd(&cur[d >> BSH], 1);
            part[pos] = ((unsigned)s << BSH) | (unsigned)(d & (BKN - 1));
        }
        return;
    }

    // ---- gemm: 2 tiles per block, shared A staging ----
    for (int i = tid; i < 1024; i += 512) {
        const int row = i >> 4, ch = i & 15;
        const uint4 vh = *(const uint4*)(ATh + row * 128 + ch * 8);
        const uint4 vl = *(const uint4*)(ATl + row * 128 + ch * 8);
        *(uint4*)(sAh + row * LDST + ch * 8) = vh;
        *(uint4*)(sAl + row * LDST + ch * 8) = vl;
    }
    __syncthreads();

    const int wave8 = tid >> 6;            // 0..7
    const int tile = (blockIdx.x - ABLK) * 2 + (wave8 >> 2);
    const int wave = wave8 & 3;            // 0..3 within tile-group
    const int lane = tid & 63;
    const int lr = lane & 15;
    const int lg = lane >> 4;

    bf16x8 bh[4][4], bl[4][4];
#pragma unroll
    for (int ct = 0; ct < 4; ++ct) {
        const int col = ct * 16 + lr;
#pragma unroll
        for (int ks = 0; ks < 4; ++ks) {
            const int k0 = ks * 32 + lg * 8;
            bh[ct][ks] = *(const bf16x8*)(sAh + col * LDST + k0);
            bl[ct][ks] = *(const bf16x8*)(sAl + col * LDST + k0);
        }
    }

    if (tile >= GEMMB) return;
    const int tilebase = tile * 64;
    const int xrowidx = tilebase + wave * 16 + lr;
    const float* xrow = x + (size_t)(xrowidx < NN ? xrowidx : NN - 1) * 128;

    f32x4 acc[4] = {f32x4{0,0,0,0}, f32x4{0,0,0,0}, f32x4{0,0,0,0}, f32x4{0,0,0,0}};
#pragma unroll
    for (int ks = 0; ks < 4; ++ks) {
        const int k0 = ks * 32 + lg * 8;
        const float4 v0 = *(const float4*)(xrow + k0);
        const float4 v1 = *(const float4*)(xrow + k0 + 4);
        const float vv[8] = {v0.x, v0.y, v0.z, v0.w, v1.x, v1.y, v1.z, v1.w};
        bf16x8 xh, xl;
#pragma unroll
        for (int j = 0; j < 8; ++j) {
            const unsigned short h = f2bf(vv[j]);
            xh[j] = (short)h;
            xl[j] = (short)f2bf(vv[j] - bf2f(h));
        }
#pragma unroll
        for (int ct = 0; ct < 4; ++ct) {
            acc[ct] = __builtin_amdgcn_mfma_f32_16x16x32_bf16(xh, bh[ct][ks], acc[ct], 0, 0, 0);
            acc[ct] = __builtin_amdgcn_mfma_f32_16x16x32_bf16(xh, bl[ct][ks], acc[ct], 0, 0, 0);
            acc[ct] = __builtin_amdgcn_mfma_f32_16x16x32_bf16(xl, bh[ct][ks], acc[ct], 0, 0, 0);
        }
    }

#pragma unroll
    for (int rg = 0; rg < 4; ++rg) {
        float m = fmaxf(fabsf(acc[0][rg]), fabsf(acc[1][rg]));
#pragma unroll
        for (int d = 1; d < 16; d <<= 1) m = fmaxf(m, __shfl_xor(m, d, 64));
        m = fmaxf(m, 1e-20f);
        const float scl = m * (1.0f / 127.0f);
        const float inv = 127.0f / m;
        const int nrow = tilebase + wave * 16 + lg * 4 + rg;
        if (nrow < NN) {
            const int q0 = __float2int_rn(acc[0][rg] * inv);
            const int q1 = __float2int_rn(acc[1][rg] * inv);
            p8[(size_t)nrow * 32 + lr]      = (signed char)q0;
            p8[(size_t)nrow * 32 + 16 + lr] = (signed char)q1;
            if (lr == 0) pscale[nrow] = scl;
            qh[(size_t)nrow * 32 + lr]      = __float2half(acc[2][rg]);
            qh[(size_t)nrow * 32 + 16 + lr] = __float2half(acc[3][rg]);
        }
    }
}

__global__ __launch_bounds__(512) void partB_build(const unsigned* __restrict__ part,
    const int* __restrict__ bbase, int* __restrict__ rowptr, int* __restrict__ cols)
{
    __shared__ int h[BKN];
    __shared__ int cur[BKN];
    __shared__ int wsum[8];
    const int b = blockIdx.x;
    const int t = threadIdx.x;
    const int beg = bbase[b], end = bbase[b + 1];
    h[t] = 0;
    __syncthreads();
    for (int e = beg + t; e < end; e += 512)
        atomicAdd(&h[part[e] & (BKN - 1u)], 1);
    __syncthreads();
    const int v = h[t];
    int inc = v;
#pragma unroll
    for (int d = 1; d < 64; d <<= 1) {
        const int u = __shfl_up(inc, d, 64);
        if ((t & 63) >= d) inc += u;
    }
    if ((t & 63) == 63) wsum[t >> 6] = inc;
    __syncthreads();
    int woff = 0;
    for (int w = 0; w < (t >> 6); ++w) woff += wsum[w];
    const int excl = inc + woff - v;
    cur[t] = excl;
    const int node = b * BKN + t;
    if (node < NN) rowptr[node] = beg + excl;
    if (b == NB - 1 && t == 0) rowptr[NN] = NE;
    __syncthreads();
    for (int e = beg + t; e < end; e += 512) {
        const unsigned w = part[e];
        const int pos = atomicAdd(&cur[w & (BKN - 1u)], 1);
        cols[beg + pos] = (int)(w >> BSH);
    }
}

// ============ aggregation via CSR (8 edge-slots x uint2 loads) ============
__global__ __launch_bounds__(256) void agg1_csr(const int* __restrict__ rowptr,
    const int* __restrict__ cols, const signed char* __restrict__ p8,
    const float* __restrict__ pscale, const __half* __restrict__ qh,
    const float* __restrict__ cbuf, __half* __restrict__ g, __half* __restrict__ r)
{
    const int node = blockIdx.x * 8 + (threadIdx.x >> 5);
    if (node >= NN) return;
    const int lane = threadIdx.x & 31;
    const int es = lane >> 2;      // edge slot 0..7
    const int k  = lane & 3;       // uint2 index 0..3 (feats 8k..8k+7)
    const int beg = rowptr[node], end = rowptr[node + 1];
    const uint2* p64 = (const uint2*)p8;
    float a0 = 0.f, a1 = 0.f, a2 = 0.f, a3 = 0.f;
    float a4 = 0.f, a5 = 0.f, a6 = 0.f, a7 = 0.f;
#pragma unroll 2
    for (int j = beg; j < end; j += 8) {
        const int jj = j + es;
        const int s = cols[(jj < end) ? jj : (end - 1)];
        const float scl = (jj < end) ? pscale[s] : 0.f;
        const uint2 w = p64[(size_t)s * 4 + k];
        a0 = fmaf((float)(signed char)(w.x & 0xffu), scl, a0);
        a1 = fmaf((float)(signed char)((w.x >> 8) & 0xffu), scl, a1);
        a2 = fmaf((float)(signed char)((w.x >> 16) & 0xffu), scl, a2);
        a3 = fmaf((float)(signed char)(w.x >> 24), scl, a3);
        a4 = fmaf((float)(signed char)(w.y & 0xffu), scl, a4);
        a5 = fmaf((float)(signed char)((w.y >> 8) & 0xffu), scl, a5);
        a6 = fmaf((float)(signed char)((w.y >> 16) & 0xffu), scl, a6);
        a7 = fmaf((float)(signed char)(w.y >> 24), scl, a7);
    }
#pragma unroll
    for (int d = 4; d <= 16; d <<= 1) {
        a0 += __shfl_xor(a0, d, 64); a1 += __shfl_xor(a1, d, 64);
        a2 += __shfl_xor(a2, d, 64); a3 += __shfl_xor(a3, d, 64);
        a4 += __shfl_xor(a4, d, 64); a5 += __shfl_xor(a5, d, 64);
        a6 += __shfl_xor(a6, d, 64); a7 += __shfl_xor(a7, d, 64);
    }
    if (es == 0) {
        // lane k holds feats 8k..8k+7
        const float dg = (float)(end - beg);
        const float inv = 1.0f / fmaxf(dg, 1.0f);
        const uint4 qw = *(const uint4*)(qh + (size_t)node * 32 + 8 * k);
        const float2 q0 = unpackh2(qw.x), q1 = unpackh2(qw.y);
        const float2 q2 = unpackh2(qw.z), q3 = unpackh2(qw.w);
        const float4 cb0 = *(const float4*)(cbuf + 8 * k);
        const float4 cb1 = *(const float4*)(cbuf + 8 * k + 4);
        const float v0 = fmaf(a0, inv, q0.x + cb0.x);
        const float v1 = fmaf(a1, inv, q0.y + cb0.y);
        const float v2 = fmaf(a2, inv, q1.x + cb0.z);
        const float v3 = fmaf(a3, inv, q1.y + cb0.w);
        const float v4 = fmaf(a4, inv, q2.x + cb1.x);
        const float v5 = fmaf(a5, inv, q2.y + cb1.y);
        const float v6 = fmaf(a6, inv, q3.x + cb1.z);
        const float v7 = fmaf(a7, inv, q3.y + cb1.w);
        uint4 ow;
        ow.x = __builtin_bit_cast(unsigned, __floats2half2_rn(v0, v1));
        ow.y = __builtin_bit_cast(unsigned, __floats2half2_rn(v2, v3));
        ow.z = __builtin_bit_cast(unsigned, __floats2half2_rn(v4, v5));
        ow.w = __builtin_bit_cast(unsigned, __floats2half2_rn(v6, v7));
        if (k < 2) *(uint4*)(g + (size_t)node * 16 + 8 * k) = ow;
        else       *(uint4*)(r + (size_t)node * 16 + 8 * (k - 2)) = ow;
    }
}

__global__ __launch_bounds__(256) void agg2_csr(const int* __restrict__ rowptr,
    const int* __restrict__ cols, const __half* __restrict__ g,
    const __half* __restrict__ r, const float* __restrict__ b2,
    __half* __restrict__ h2)
{
    const int node = blockIdx.x * 8 + (threadIdx.x >> 5);
    if (node >= NN) return;
    const int lane = threadIdx.x & 31;
    const int es = lane >> 2;
    const int k  = lane & 3;       // feats 4k..4k+3
    const int beg = rowptr[node], end = rowptr[node + 1];
    const uint2* g64 = (const uint2*)g;
    float a0 = 0.f, a1 = 0.f, a2 = 0.f, a3 = 0.f;
#pragma unroll 2
    for (int j = beg; j < end; j += 8) {
        const int jj = j + es;
        const int s = cols[(jj < end) ? jj : (end - 1)];
        const float m = (jj < end) ? 1.0f : 0.0f;
        const uint2 w = g64[(size_t)s * 4 + k];
        const float2 v0 = unpackh2(w.x);
        const float2 v1 = unpackh2(w.y);
        a0 = fmaf(v0.x, m, a0);
        a1 = fmaf(v0.y, m, a1);
        a2 = fmaf(v1.x, m, a2);
        a3 = fmaf(v1.y, m, a3);
    }
#pragma unroll
    for (int d = 4; d <= 16; d <<= 1) {
        a0 += __shfl_xor(a0, d, 64); a1 += __shfl_xor(a1, d, 64);
        a2 += __shfl_xor(a2, d, 64); a3 += __shfl_xor(a3, d, 64);
    }
    if (es == 0) {
        const float dg = (float)(end - beg);
        const float inv = 1.0f / fmaxf(dg, 1.0f);
        const uint2 rw = ((const uint2*)r)[(size_t)node * 4 + k];
        const float2 r0 = unpackh2(rw.x), r1 = unpackh2(rw.y);
        const float4 bb = *(const float4*)(b2 + 4 * k);
        const float v0 = fmaf(a0, inv, r0.x + bb.x);
        const float v1 = fmaf(a1, inv, r0.y + bb.y);
        const float v2 = fmaf(a2, inv, r1.x + bb.z);
        const float v3 = fmaf(a3, inv, r1.y + bb.w);
        uint2 ow;
        ow.x = __builtin_bit_cast(unsigned, __floats2half2_rn(v0, v1));
        ow.y = __builtin_bit_cast(unsigned, __floats2half2_rn(v2, v3));
        ((uint2*)h2)[(size_t)node * 4 + k] = ow;
    }
}

// ---- out = sigmoid( sum_k h2[s][k]*h2[d][k]*v[k] + c ); 4 edges per thread
__global__ __launch_bounds__(256) void edge_mlp(const int* __restrict__ src,
    const int* __restrict__ dst, const __half* __restrict__ h2,
    const float* __restrict__ cbuf, float* __restrict__ out)
{
    __shared__ float sv[17];
    if (threadIdx.x < 16) sv[threadIdx.x] = cbuf[32 + threadIdx.x];
    if (threadIdx.x == 16) sv[16] = cbuf[48];
    __syncthreads();
    const int ebase = blockIdx.x * 1024 + threadIdx.x;
#pragma unroll
    for (int u = 0; u < 4; ++u) {
        const int e = ebase + u * 256;
        if (e >= NE) return;
        const int s = src[e], d = dst[e];
        const uint4* hs = (const uint4*)(h2 + (size_t)s * 16);
        const uint4* hd = (const uint4*)(h2 + (size_t)d * 16);
        const uint4 a0 = hs[0], a1 = hs[1];
        const uint4 b0 = hd[0], b1 = hd[1];
        const unsigned aw[8] = {a0.x, a0.y, a0.z, a0.w, a1.x, a1.y, a1.z, a1.w};
        const unsigned bw[8] = {b0.x, b0.y, b0.z, b0.w, b1.x, b1.y, b1.z, b1.w};
        float acc = sv[16];
#pragma unroll
        for (int qq = 0; qq < 8; ++qq) {
            const float2 a = unpackh2(aw[qq]);
            const float2 b = unpackh2(bw[qq]);
            acc = fmaf(a.x * b.x, sv[qq * 2 + 0], acc);
            acc = fmaf(a.y * b.y, sv[qq * 2 + 1], acc);
        }
        out[e] = 1.0f / (1.0f + __expf(-acc));
    }
}

extern "C" void kernel_launch(void* const* d_in, const int* in_sizes, int n_in,
                              void* d_out, int out_size, void* d_ws, size_t ws_size,
                              hipStream_t stream)
{
    const float* x    = (const float*)d_in[0];
    const int*   ei   = (const int*)d_in[1];
    const float* w1l  = (const float*)d_in[2];
    const float* w1r  = (const float*)d_in[3];
    const float* b1   = (const float*)d_in[4];
    const float* w2l  = (const float*)d_in[5];
    const float* w2r  = (const float*)d_in[6];
    const float* b2   = (const float*)d_in[7];
    const float* fc1w = (const float*)d_in[8];
    const float* fc1b = (const float*)d_in[9];
    const float* fc2w = (const float*)d_in[10];
    const float* fc2b = (const float*)d_in[11];
    float* out = (float*)d_out;

    const int* src = ei;
    const int* dst = ei + NE;

    // workspace layout (int units)
    int* W = (int*)d_ws;
    size_t o = 0;
#define ALIGN16() o = (o + 15) & ~(size_t)15
    int* mat    = W + o; o += (size_t)NB * ABLK; ALIGN16();
    int* bbase  = W + o; o += NB + 1;            ALIGN16();
    int* rowptr = W + o; o += NN + 1;            ALIGN16();
    unsigned* part = (unsigned*)(W + o); o += NE; ALIGN16();
    int* cols   = W + o; o += NE;                ALIGN16();
    unsigned short* ATh = (unsigned short*)(W + o); o += 4096; ALIGN16();
    unsigned short* ATl = (unsigned short*)(W + o); o += 4096; ALIGN16();
    float* cbuf = (float*)(W + o); o += 64;      ALIGN16();
    signed char* p8 = (signed char*)(W + o); o += (size_t)NN * 8;  ALIGN16();
    float* pscale   = (float*)(W + o); o += NN;  ALIGN16();
    __half* qh  = (__half*)(W + o); o += (size_t)NN * 16; ALIGN16();
    __half* g   = (__half*)(W + o); o += (size_t)NN * 8;  ALIGN16();
    __half* r   = (__half*)(W + o); o += (size_t)NN * 8;  ALIGN16();
    __half* h2  = (__half*)(W + o); o += (size_t)NN * 8;  ALIGN16();

    // K1: count || precomp
    fused0<<<ABLK + 129, 256, 0, stream>>>(dst, w1l, w1r, w2l, w2r, b1,
                                           fc1w, fc1b, fc2w, fc2b, mat, ATh, ATl, cbuf);
    // K2: scan
    scan_all<<<1, 256, 0, stream>>>(mat, bbase);
    // K3: scatter || gemm (512 threads; gemm 2 tiles/block, LDS-staged)
    fused1<<<ABLK + GBLK, 512, 0, stream>>>(src, dst, mat, bbase, part,
                                            x, ATh, ATl, p8, pscale, qh);
    // K4: per-bucket CSR
    partB_build<<<NB, 512, 0, stream>>>(part, bbase, rowptr, cols);
    // K5/K6: aggregations (uint2 gathers, 8 edge-slots)
    agg1_csr<<<(NN + 7) / 8, 256, 0, stream>>>(rowptr, cols, p8, pscale, qh, cbuf, g, r);
    agg2_csr<<<(NN + 7) / 8, 256, 0, stream>>>(rowptr, cols, g, r, b2, h2);
    // K7: head (4 edges/thread)
    edge_mlp<<<(NE + 1023) / 1024, 256, 0, stream>>>(src, dst, h2, cbuf, out);
}

// Round 20
// 126.485 us; speedup vs baseline: 1.2340x; 1.0893x over previous
//
#include <hip/hip_runtime.h>
#include <hip/hip_fp16.h>
#include <math.h>

#define NN 100000
#define NE 1600000

#define BSH  9          // bucket = dst >> 9
#define BKN  512        // nodes per bucket
#define NB   196        // ceil(NN/512)
#define ABLK 128        // partition blocks  (EPB/NB ~ 64-entry runs = 256B, WC-safe)
#define EPB  ((NE + ABLK - 1) / ABLK)   // 12500 edges per partition block
#define GEMMB ((NN + 63) / 64)          // 1563 gemm tiles
#define GBLK ((GEMMB + 1) / 2)          // 782 gemm blocks (2 tiles each)
#define LDST 136

typedef __attribute__((ext_vector_type(8))) short bf16x8;
typedef __attribute__((ext_vector_type(4))) float f32x4;

__device__ __forceinline__ unsigned short f2bf(float f) {
    unsigned u = __builtin_bit_cast(unsigned, f);
    u += 0x7fffu + ((u >> 16) & 1u);           // RNE
    return (unsigned short)(u >> 16);
}
__device__ __forceinline__ float bf2f(unsigned short h) {
    unsigned u = ((unsigned)h) << 16;
    return __builtin_bit_cast(float, u);
}
__device__ __forceinline__ float2 unpackh2(unsigned w) {
    const __half2 h = __builtin_bit_cast(__half2, w);
    return __half22float2(h);
}

// ============ K1: fused count (blocks 0..127) + precomp (128..256) ============
__global__ __launch_bounds__(256) void fused0(const int* __restrict__ dst,
    const float* __restrict__ w1l, const float* __restrict__ w1r,
    const float* __restrict__ w2l, const float* __restrict__ w2r,
    const float* __restrict__ b1, const float* __restrict__ fc1w,
    const float* __restrict__ fc1b, const float* __restrict__ fc2w,
    const float* __restrict__ fc2b, int* __restrict__ mat,
    unsigned short* __restrict__ ATh, unsigned short* __restrict__ ATl,
    float* __restrict__ cbuf)
{
    __shared__ int h[NB];
    __shared__ float sl[64], sr[64];
    const int t = threadIdx.x;
    if (blockIdx.x < ABLK) {
        for (int i = t; i < NB; i += 256) h[i] = 0;
        __syncthreads();
        const int a = blockIdx.x;
        const int beg = a * EPB;
        const int end = (beg + EPB < NE) ? beg + EPB : NE;
        int e = beg + t;
        for (; e + 3 * 256 < end; e += 4 * 256) {
            const int d0 = dst[e], d1 = dst[e + 256], d2 = dst[e + 512], d3 = dst[e + 768];
            atomicAdd(&h[d0 >> BSH], 1);
            atomicAdd(&h[d1 >> BSH], 1);
            atomicAdd(&h[d2 >> BSH], 1);
            atomicAdd(&h[d3 >> BSH], 1);
        }
        for (; e < end; e += 256)
            atomicAdd(&h[dst[e] >> BSH], 1);
        __syncthreads();
        for (int i = t; i < NB; i += 256) mat[(size_t)i * ABLK + a] = h[i];
        return;
    }
    if (blockIdx.x < ABLK + 128) {
        const int k = blockIdx.x - ABLK;
        const int j = t;
        if (j < 64) { sl[j] = w1l[k * 64 + j]; sr[j] = w1r[k * 64 + j]; }
        __syncthreads();
        if (j < 64) {
            const int sel = j >> 4, jj = j & 15;
            const float* row = (sel < 2) ? sl : sr;
            const float* w2  = (sel & 1) ? w2r : w2l;
            float acc = 0.f;
#pragma unroll
            for (int m = 0; m < 64; ++m) acc = fmaf(row[m], w2[m * 16 + jj], acc);
            const unsigned short hh = f2bf(acc);
            ATh[j * 128 + k] = hh;                  // transposed: [col][k]
            ATl[j * 128 + k] = f2bf(acc - bf2f(hh));
        }
        return;
    }
    const int j = t;
    if (j < 16) {
        float a = 0.f;
        for (int m = 0; m < 64; ++m) a = fmaf(b1[m], w2l[m * 16 + j], a);
        cbuf[j] = a;
    } else if (j < 32) {
        const int jj = j - 16;
        float a = 0.f;
        for (int m = 0; m < 64; ++m) a = fmaf(b1[m], w2r[m * 16 + jj], a);
        cbuf[j] = a;
    } else if (j < 48) {
        const int k = j - 32;
        float a = 0.f;
        for (int m = 0; m < 8; ++m) a = fmaf(fc1w[k * 8 + m], fc2w[m], a);
        cbuf[j] = a;
    } else if (j == 48) {
        float a = fc2b[0];
        for (int m = 0; m < 8; ++m) a = fmaf(fc1b[m], fc2w[m], a);
        cbuf[48] = a;
    }
}

// single 256-thread block: per-bucket prefix over ABLK + block-scan of totals
__global__ __launch_bounds__(256) void scan_all(int* __restrict__ mat,
    int* __restrict__ bbase)
{
    __shared__ int s[256];
    const int t = threadIdx.x;
    int run = 0;
    if (t < NB) {
        int* col = mat + (size_t)t * ABLK;
        for (int a = 0; a < ABLK; ++a) { const int v = col[a]; col[a] = run; run += v; }
    }
    s[t] = (t < NB) ? run : 0;
    __syncthreads();
    for (int off = 1; off < 256; off <<= 1) {
        const int u = (t >= off) ? s[t - off] : 0;
        __syncthreads();
        s[t] += u;
        __syncthreads();
    }
    if (t < NB) bbase[t] = s[t] - run;         // exclusive
    if (t == NB - 1) bbase[NB] = s[t];         // == NE
}

// ============ K3: fused scatter (blocks 0..127) + MFMA gemm (128..) ============
__global__ __launch_bounds__(512) void fused1(const int* __restrict__ src,
    const int* __restrict__ dst, const int* __restrict__ mat,
    const int* __restrict__ bbase, unsigned* __restrict__ part,
    const float* __restrict__ x, const unsigned short* __restrict__ ATh,
    const unsigned short* __restrict__ ATl, signed char* __restrict__ p8,
    float* __restrict__ pscale, __half* __restrict__ qh)
{
    __shared__ unsigned short sAh[64 * LDST];
    __shared__ unsigned short sAl[64 * LDST];
    __shared__ int cur[NB];
    const int tid = threadIdx.x;

    if (blockIdx.x < ABLK) {
        // ---- partA_scatter (4x unrolled: 4 independent latency chains) ----
        const int a = blockIdx.x;
        for (int i = tid; i < NB; i += 512)
            cur[i] = mat[(size_t)i * ABLK + a] + bbase[i];
        __syncthreads();
        const int beg = a * EPB;
        const int end = (beg + EPB < NE) ? beg + EPB : NE;
        int e = beg + tid;
        for (; e + 3 * 512 < end; e += 4 * 512) {
            const int s0 = src[e],          d0 = dst[e];
            const int s1 = src[e + 512],    d1 = dst[e + 512];
            const int s2 = src[e + 1024],   d2 = dst[e + 1024];
            const int s3 = src[e + 1536],   d3 = dst[e + 1536];
            const int p0 = atomicAdd(&cur[d0 >> BSH], 1);
            const int p1 = atomicAdd(&cur[d1 >> BSH], 1);
            const int p2 = atomicAdd(&cur[d2 >> BSH], 1);
            const int p3 = atomicAdd(&cur[d3 >> BSH], 1);
            part[p0] = ((unsigned)s0 << BSH) | (unsigned)(d0 & (BKN - 1));
            part[p1] = ((unsigned)s1 << BSH) | (unsigned)(d1 & (BKN - 1));
            part[p2] = ((unsigned)s2 << BSH) | (unsigned)(d2 & (BKN - 1));
            part[p3] = ((unsigned)s3 << BSH) | (unsigned)(d3 & (BKN - 1));
        }
        for (; e < end; e += 512) {
            const int s = src[e], d = dst[e];
            const int pos = atomicAdd(&cur[d >> BSH], 1);
            part[pos] = ((unsigned)s << BSH) | (unsigned)(d & (BKN - 1));
        }
        return;
    }

    // ---- gemm: 2 tiles per block, shared A staging ----
    for (int i = tid; i < 1024; i += 512) {
        const int row = i >> 4, ch = i & 15;
        const uint4 vh = *(const uint4*)(ATh + row * 128 + ch * 8);
        const uint4 vl = *(const uint4*)(ATl + row * 128 + ch * 8);
        *(uint4*)(sAh + row * LDST + ch * 8) = vh;
        *(uint4*)(sAl + row * LDST + ch * 8) = vl;
    }
    __syncthreads();

    const int wave8 = tid >> 6;            // 0..7
    const int tile = (blockIdx.x - ABLK) * 2 + (wave8 >> 2);
    const int wave = wave8 & 3;            // 0..3 within tile-group
    const int lane = tid & 63;
    const int lr = lane & 15;
    const int lg = lane >> 4;

    bf16x8 bh[4][4], bl[4][4];
#pragma unroll
    for (int ct = 0; ct < 4; ++ct) {
        const int col = ct * 16 + lr;
#pragma unroll
        for (int ks = 0; ks < 4; ++ks) {
            const int k0 = ks * 32 + lg * 8;
            bh[ct][ks] = *(const bf16x8*)(sAh + col * LDST + k0);
            bl[ct][ks] = *(const bf16x8*)(sAl + col * LDST + k0);
        }
    }

    if (tile >= GEMMB) return;
    const int tilebase = tile * 64;
    const int xrowidx = tilebase + wave * 16 + lr;
    const float* xrow = x + (size_t)(xrowidx < NN ? xrowidx : NN - 1) * 128;

    f32x4 acc[4] = {f32x4{0,0,0,0}, f32x4{0,0,0,0}, f32x4{0,0,0,0}, f32x4{0,0,0,0}};
#pragma unroll
    for (int ks = 0; ks < 4; ++ks) {
        const int k0 = ks * 32 + lg * 8;
        const float4 v0 = *(const float4*)(xrow + k0);
        const float4 v1 = *(const float4*)(xrow + k0 + 4);
        const float vv[8] = {v0.x, v0.y, v0.z, v0.w, v1.x, v1.y, v1.z, v1.w};
        bf16x8 xh, xl;
#pragma unroll
        for (int j = 0; j < 8; ++j) {
            const unsigned short h = f2bf(vv[j]);
            xh[j] = (short)h;
            xl[j] = (short)f2bf(vv[j] - bf2f(h));
        }
#pragma unroll
        for (int ct = 0; ct < 4; ++ct) {
            acc[ct] = __builtin_amdgcn_mfma_f32_16x16x32_bf16(xh, bh[ct][ks], acc[ct], 0, 0, 0);
            acc[ct] = __builtin_amdgcn_mfma_f32_16x16x32_bf16(xh, bl[ct][ks], acc[ct], 0, 0, 0);
            acc[ct] = __builtin_amdgcn_mfma_f32_16x16x32_bf16(xl, bh[ct][ks], acc[ct], 0, 0, 0);
        }
    }

#pragma unroll
    for (int rg = 0; rg < 4; ++rg) {
        float m = fmaxf(fabsf(acc[0][rg]), fabsf(acc[1][rg]));
#pragma unroll
        for (int d = 1; d < 16; d <<= 1) m = fmaxf(m, __shfl_xor(m, d, 64));
        m = fmaxf(m, 1e-20f);
        const float scl = m * (1.0f / 127.0f);
        const float inv = 127.0f / m;
        const int nrow = tilebase + wave * 16 + lg * 4 + rg;
        if (nrow < NN) {
            const int q0 = __float2int_rn(acc[0][rg] * inv);
            const int q1 = __float2int_rn(acc[1][rg] * inv);
            p8[(size_t)nrow * 32 + lr]      = (signed char)q0;
            p8[(size_t)nrow * 32 + 16 + lr] = (signed char)q1;
            if (lr == 0) pscale[nrow] = scl;
            qh[(size_t)nrow * 32 + lr]      = __float2half(acc[2][rg]);
            qh[(size_t)nrow * 32 + 16 + lr] = __float2half(acc[3][rg]);
        }
    }
}

__global__ __launch_bounds__(512) void partB_build(const unsigned* __restrict__ part,
    const int* __restrict__ bbase, int* __restrict__ rowptr, int* __restrict__ cols)
{
    __shared__ int h[BKN];
    __shared__ int cur[BKN];
    __shared__ int wsum[8];
    const int b = blockIdx.x;
    const int t = threadIdx.x;
    const int beg = bbase[b], end = bbase[b + 1];
    h[t] = 0;
    __syncthreads();
    {
        int e = beg + t;
        for (; e + 3 * 512 < end; e += 4 * 512) {
            const unsigned w0 = part[e], w1 = part[e + 512];
            const unsigned w2 = part[e + 1024], w3 = part[e + 1536];
            atomicAdd(&h[w0 & (BKN - 1u)], 1);
            atomicAdd(&h[w1 & (BKN - 1u)], 1);
            atomicAdd(&h[w2 & (BKN - 1u)], 1);
            atomicAdd(&h[w3 & (BKN - 1u)], 1);
        }
        for (; e < end; e += 512)
            atomicAdd(&h[part[e] & (BKN - 1u)], 1);
    }
    __syncthreads();
    const int v = h[t];
    int inc = v;
#pragma unroll
    for (int d = 1; d < 64; d <<= 1) {
        const int u = __shfl_up(inc, d, 64);
        if ((t & 63) >= d) inc += u;
    }
    if ((t & 63) == 63) wsum[t >> 6] = inc;
    __syncthreads();
    int woff = 0;
    for (int w = 0; w < (t >> 6); ++w) woff += wsum[w];
    const int excl = inc + woff - v;
    cur[t] = excl;
    const int node = b * BKN + t;
    if (node < NN) rowptr[node] = beg + excl;
    if (b == NB - 1 && t == 0) rowptr[NN] = NE;
    __syncthreads();
    {
        int e = beg + t;
        for (; e + 3 * 512 < end; e += 4 * 512) {
            const unsigned w0 = part[e], w1 = part[e + 512];
            const unsigned w2 = part[e + 1024], w3 = part[e + 1536];
            const int p0 = atomicAdd(&cur[w0 & (BKN - 1u)], 1);
            const int p1 = atomicAdd(&cur[w1 & (BKN - 1u)], 1);
            const int p2 = atomicAdd(&cur[w2 & (BKN - 1u)], 1);
            const int p3 = atomicAdd(&cur[w3 & (BKN - 1u)], 1);
            cols[beg + p0] = (int)(w0 >> BSH);
            cols[beg + p1] = (int)(w1 >> BSH);
            cols[beg + p2] = (int)(w2 >> BSH);
            cols[beg + p3] = (int)(w3 >> BSH);
        }
        for (; e < end; e += 512) {
            const unsigned w = part[e];
            const int pos = atomicAdd(&cur[w & (BKN - 1u)], 1);
            cols[beg + pos] = (int)(w >> BSH);
        }
    }
}

// ============ aggregation via CSR (8 edge-slots x uint2 loads) ============
__global__ __launch_bounds__(256) void agg1_csr(const int* __restrict__ rowptr,
    const int* __restrict__ cols, const signed char* __restrict__ p8,
    const float* __restrict__ pscale, const __half* __restrict__ qh,
    const float* __restrict__ cbuf, __half* __restrict__ g, __half* __restrict__ r)
{
    const int node = blockIdx.x * 8 + (threadIdx.x >> 5);
    if (node >= NN) return;
    const int lane = threadIdx.x & 31;
    const int es = lane >> 2;      // edge slot 0..7
    const int k  = lane & 3;       // uint2 index 0..3 (feats 8k..8k+7)
    const int beg = rowptr[node], end = rowptr[node + 1];
    const uint2* p64 = (const uint2*)p8;
    float a0 = 0.f, a1 = 0.f, a2 = 0.f, a3 = 0.f;
    float a4 = 0.f, a5 = 0.f, a6 = 0.f, a7 = 0.f;
#pragma unroll 2
    for (int j = beg; j < end; j += 8) {
        const int jj = j + es;
        const int s = cols[(jj < end) ? jj : (end - 1)];
        const float scl = (jj < end) ? pscale[s] : 0.f;
        const uint2 w = p64[(size_t)s * 4 + k];
        a0 = fmaf((float)(signed char)(w.x & 0xffu), scl, a0);
        a1 = fmaf((float)(signed char)((w.x >> 8) & 0xffu), scl, a1);
        a2 = fmaf((float)(signed char)((w.x >> 16) & 0xffu), scl, a2);
        a3 = fmaf((float)(signed char)(w.x >> 24), scl, a3);
        a4 = fmaf((float)(signed char)(w.y & 0xffu), scl, a4);
        a5 = fmaf((float)(signed char)((w.y >> 8) & 0xffu), scl, a5);
        a6 = fmaf((float)(signed char)((w.y >> 16) & 0xffu), scl, a6);
        a7 = fmaf((float)(signed char)(w.y >> 24), scl, a7);
    }
#pragma unroll
    for (int d = 4; d <= 16; d <<= 1) {
        a0 += __shfl_xor(a0, d, 64); a1 += __shfl_xor(a1, d, 64);
        a2 += __shfl_xor(a2, d, 64); a3 += __shfl_xor(a3, d, 64);
        a4 += __shfl_xor(a4, d, 64); a5 += __shfl_xor(a5, d, 64);
        a6 += __shfl_xor(a6, d, 64); a7 += __shfl_xor(a7, d, 64);
    }
    if (es == 0) {
        // lane k holds feats 8k..8k+7
        const float dg = (float)(end - beg);
        const float inv = 1.0f / fmaxf(dg, 1.0f);
        const uint4 qw = *(const uint4*)(qh + (size_t)node * 32 + 8 * k);
        const float2 q0 = unpackh2(qw.x), q1 = unpackh2(qw.y);
        const float2 q2 = unpackh2(qw.z), q3 = unpackh2(qw.w);
        const float4 cb0 = *(const float4*)(cbuf + 8 * k);
        const float4 cb1 = *(const float4*)(cbuf + 8 * k + 4);
        const float v0 = fmaf(a0, inv, q0.x + cb0.x);
        const float v1 = fmaf(a1, inv, q0.y + cb0.y);
        const float v2 = fmaf(a2, inv, q1.x + cb0.z);
        const float v3 = fmaf(a3, inv, q1.y + cb0.w);
        const float v4 = fmaf(a4, inv, q2.x + cb1.x);
        const float v5 = fmaf(a5, inv, q2.y + cb1.y);
        const float v6 = fmaf(a6, inv, q3.x + cb1.z);
        const float v7 = fmaf(a7, inv, q3.y + cb1.w);
        uint4 ow;
        ow.x = __builtin_bit_cast(unsigned, __floats2half2_rn(v0, v1));
        ow.y = __builtin_bit_cast(unsigned, __floats2half2_rn(v2, v3));
        ow.z = __builtin_bit_cast(unsigned, __floats2half2_rn(v4, v5));
        ow.w = __builtin_bit_cast(unsigned, __floats2half2_rn(v6, v7));
        if (k < 2) *(uint4*)(g + (size_t)node * 16 + 8 * k) = ow;
        else       *(uint4*)(r + (size_t)node * 16 + 8 * (k - 2)) = ow;
    }
}

__global__ __launch_bounds__(256) void agg2_csr(const int* __restrict__ rowptr,
    const int* __restrict__ cols, const __half* __restrict__ g,
    const __half* __restrict__ r, const float* __restrict__ b2,
    __half* __restrict__ h2)
{
    const int node = blockIdx.x * 8 + (threadIdx.x >> 5);
    if (node >= NN) return;
    const int lane = threadIdx.x & 31;
    const int es = lane >> 2;
    const int k  = lane & 3;       // feats 4k..4k+3
    const int beg = rowptr[node], end = rowptr[node + 1];
    const uint2* g64 = (const uint2*)g;
    float a0 = 0.f, a1 = 0.f, a2 = 0.f, a3 = 0.f;
#pragma unroll 2
    for (int j = beg; j < end; j += 8) {
        const int jj = j + es;
        const int s = cols[(jj < end) ? jj : (end - 1)];
        const float m = (jj < end) ? 1.0f : 0.0f;
        const uint2 w = g64[(size_t)s * 4 + k];
        const float2 v0 = unpackh2(w.x);
        const float2 v1 = unpackh2(w.y);
        a0 = fmaf(v0.x, m, a0);
        a1 = fmaf(v0.y, m, a1);
        a2 = fmaf(v1.x, m, a2);
        a3 = fmaf(v1.y, m, a3);
    }
#pragma unroll
    for (int d = 4; d <= 16; d <<= 1) {
        a0 += __shfl_xor(a0, d, 64); a1 += __shfl_xor(a1, d, 64);
        a2 += __shfl_xor(a2, d, 64); a3 += __shfl_xor(a3, d, 64);
    }
    if (es == 0) {
        const float dg = (float)(end - beg);
        const float inv = 1.0f / fmaxf(dg, 1.0f);
        const uint2 rw = ((const uint2*)r)[(size_t)node * 4 + k];
        const float2 r0 = unpackh2(rw.x), r1 = unpackh2(rw.y);
        const float4 bb = *(const float4*)(b2 + 4 * k);
        const float v0 = fmaf(a0, inv, r0.x + bb.x);
        const float v1 = fmaf(a1, inv, r0.y + bb.y);
        const float v2 = fmaf(a2, inv, r1.x + bb.z);
        const float v3 = fmaf(a3, inv, r1.y + bb.w);
        uint2 ow;
        ow.x = __builtin_bit_cast(unsigned, __floats2half2_rn(v0, v1));
        ow.y = __builtin_bit_cast(unsigned, __floats2half2_rn(v2, v3));
        ((uint2*)h2)[(size_t)node * 4 + k] = ow;
    }
}

// ---- out = sigmoid( sum_k h2[s][k]*h2[d][k]*v[k] + c ); 4 edges per thread
__global__ __launch_bounds__(256) void edge_mlp(const int* __restrict__ src,
    const int* __restrict__ dst, const __half* __restrict__ h2,
    const float* __restrict__ cbuf, float* __restrict__ out)
{
    __shared__ float sv[17];
    if (threadIdx.x < 16) sv[threadIdx.x] = cbuf[32 + threadIdx.x];
    if (threadIdx.x == 16) sv[16] = cbuf[48];
    __syncthreads();
    const int ebase = blockIdx.x * 1024 + threadIdx.x;
#pragma unroll
    for (int u = 0; u < 4; ++u) {
        const int e = ebase + u * 256;
        if (e >= NE) return;
        const int s = src[e], d = dst[e];
        const uint4* hs = (const uint4*)(h2 + (size_t)s * 16);
        const uint4* hd = (const uint4*)(h2 + (size_t)d * 16);
        const uint4 a0 = hs[0], a1 = hs[1];
        const uint4 b0 = hd[0], b1 = hd[1];
        const unsigned aw[8] = {a0.x, a0.y, a0.z, a0.w, a1.x, a1.y, a1.z, a1.w};
        const unsigned bw[8] = {b0.x, b0.y, b0.z, b0.w, b1.x, b1.y, b1.z, b1.w};
        float acc = sv[16];
#pragma unroll
        for (int qq = 0; qq < 8; ++qq) {
            const float2 a = unpackh2(aw[qq]);
            const float2 b = unpackh2(bw[qq]);
            acc = fmaf(a.x * b.x, sv[qq * 2 + 0], acc);
            acc = fmaf(a.y * b.y, sv[qq * 2 + 1], acc);
        }
        out[e] = 1.0f / (1.0f + __expf(-acc));
    }
}

extern "C" void kernel_launch(void* const* d_in, const int* in_sizes, int n_in,
                              void* d_out, int out_size, void* d_ws, size_t ws_size,
                              hipStream_t stream)
{
    const float* x    = (const float*)d_in[0];
    const int*   ei   = (const int*)d_in[1];
    const float* w1l  = (const float*)d_in[2];
    const float* w1r  = (const float*)d_in[3];
    const float* b1   = (const float*)d_in[4];
    const float* w2l  = (const float*)d_in[5];
    const float* w2r  = (const float*)d_in[6];
    const float* b2   = (const float*)d_in[7];
    const float* fc1w = (const float*)d_in[8];
    const float* fc1b = (const float*)d_in[9];
    const float* fc2w = (const float*)d_in[10];
    const float* fc2b = (const float*)d_in[11];
    float* out = (float*)d_out;

    const int* src = ei;
    const int* dst = ei + NE;

    // workspace layout (int units)
    int* W = (int*)d_ws;
    size_t o = 0;
#define ALIGN16() o = (o + 15) & ~(size_t)15
    int* mat    = W + o; o += (size_t)NB * ABLK; ALIGN16();
    int* bbase  = W + o; o += NB + 1;            ALIGN16();
    int* rowptr = W + o; o += NN + 1;            ALIGN16();
    unsigned* part = (unsigned*)(W + o); o += NE; ALIGN16();
    int* cols   = W + o; o += NE;                ALIGN16();
    unsigned short* ATh = (unsigned short*)(W + o); o += 4096; ALIGN16();
    unsigned short* ATl = (unsigned short*)(W + o); o += 4096; ALIGN16();
    float* cbuf = (float*)(W + o); o += 64;      ALIGN16();
    signed char* p8 = (signed char*)(W + o); o += (size_t)NN * 8;  ALIGN16();
    float* pscale   = (float*)(W + o); o += NN;  ALIGN16();
    __half* qh  = (__half*)(W + o); o += (size_t)NN * 16; ALIGN16();
    __half* g   = (__half*)(W + o); o += (size_t)NN * 8;  ALIGN16();
    __half* r   = (__half*)(W + o); o += (size_t)NN * 8;  ALIGN16();
    __half* h2  = (__half*)(W + o); o += (size_t)NN * 8;  ALIGN16();

    // K1: count || precomp
    fused0<<<ABLK + 129, 256, 0, stream>>>(dst, w1l, w1r, w2l, w2r, b1,
                                           fc1w, fc1b, fc2w, fc2b, mat, ATh, ATl, cbuf);
    // K2: scan
    scan_all<<<1, 256, 0, stream>>>(mat, bbase);
    // K3: scatter || gemm (512 threads; gemm 2 tiles/block, LDS-staged)
    fused1<<<ABLK + GBLK, 512, 0, stream>>>(src, dst, mat, bbase, part,
                                            x, ATh, ATl, p8, pscale, qh);
    // K4: per-bucket CSR
    partB_build<<<NB, 512, 0, stream>>>(part, bbase, rowptr, cols);
    // K5/K6: aggregations (uint2 gathers, 8 edge-slots)
    agg1_csr<<<(NN + 7) / 8, 256, 0, stream>>>(rowptr, cols, p8, pscale, qh, cbuf, g, r);
    agg2_csr<<<(NN + 7) / 8, 256, 0, stream>>>(rowptr, cols, g, r, b2, h2);
    // K7: head (4 edges/thread)
    edge_mlp<<<(NE + 1023) / 1024, 256, 0, stream>>>(src, dst, h2, cbuf, out);
}

// Round 21
// 126.159 us; speedup vs baseline: 1.2372x; 1.0026x over previous
//
#include <hip/hip_runtime.h>
#include <hip/hip_fp16.h>
#include <math.h>

#define NN 100000
#define NE 1600000

#define BSH  9          // bucket = dst >> 9
#define BKN  512        // nodes per bucket
#define NB   196        // ceil(NN/512)
#define ABLK 128        // partition blocks  (EPB/NB ~ 64-entry runs = 256B, WC-safe)
#define EPB  ((NE + ABLK - 1) / ABLK)   // 12500 edges per partition block
#define GEMMB ((NN + 63) / 64)          // 1563 gemm tiles
#define GBLK ((GEMMB + 1) / 2)          // 782 gemm blocks (2 tiles each)
#define LDST 136

typedef __attribute__((ext_vector_type(8))) short bf16x8;
typedef __attribute__((ext_vector_type(4))) float f32x4;

__device__ __forceinline__ unsigned short f2bf(float f) {
    unsigned u = __builtin_bit_cast(unsigned, f);
    u += 0x7fffu + ((u >> 16) & 1u);           // RNE
    return (unsigned short)(u >> 16);
}
__device__ __forceinline__ float bf2f(unsigned short h) {
    unsigned u = ((unsigned)h) << 16;
    return __builtin_bit_cast(float, u);
}
__device__ __forceinline__ float2 unpackh2(unsigned w) {
    const __half2 h = __builtin_bit_cast(__half2, w);
    return __half22float2(h);
}

// ============ K1: fused count (blocks 0..127) + precomp (128..256) ============
__global__ __launch_bounds__(256) void fused0(const int* __restrict__ dst,
    const float* __restrict__ w1l, const float* __restrict__ w1r,
    const float* __restrict__ w2l, const float* __restrict__ w2r,
    const float* __restrict__ b1, const float* __restrict__ fc1w,
    const float* __restrict__ fc1b, const float* __restrict__ fc2w,
    const float* __restrict__ fc2b, int* __restrict__ mat,
    unsigned short* __restrict__ ATh, unsigned short* __restrict__ ATl,
    float* __restrict__ cbuf)
{
    __shared__ int h[NB];
    __shared__ float sl[64], sr[64];
    const int t = threadIdx.x;
    if (blockIdx.x < ABLK) {
        for (int i = t; i < NB; i += 256) h[i] = 0;
        __syncthreads();
        const int a = blockIdx.x;
        const int beg = a * EPB;
        const int end = (beg + EPB < NE) ? beg + EPB : NE;
        int e = beg + t;
        for (; e + 3 * 256 < end; e += 4 * 256) {
            const int d0 = dst[e], d1 = dst[e + 256], d2 = dst[e + 512], d3 = dst[e + 768];
            atomicAdd(&h[d0 >> BSH], 1);
            atomicAdd(&h[d1 >> BSH], 1);
            atomicAdd(&h[d2 >> BSH], 1);
            atomicAdd(&h[d3 >> BSH], 1);
        }
        for (; e < end; e += 256)
            atomicAdd(&h[dst[e] >> BSH], 1);
        __syncthreads();
        for (int i = t; i < NB; i += 256) mat[(size_t)i * ABLK + a] = h[i];
        return;
    }
    if (blockIdx.x < ABLK + 128) {
        const int k = blockIdx.x - ABLK;
        const int j = t;
        if (j < 64) { sl[j] = w1l[k * 64 + j]; sr[j] = w1r[k * 64 + j]; }
        __syncthreads();
        if (j < 64) {
            const int sel = j >> 4, jj = j & 15;
            const float* row = (sel < 2) ? sl : sr;
            const float* w2  = (sel & 1) ? w2r : w2l;
            float acc = 0.f;
#pragma unroll
            for (int m = 0; m < 64; ++m) acc = fmaf(row[m], w2[m * 16 + jj], acc);
            const unsigned short hh = f2bf(acc);
            ATh[j * 128 + k] = hh;                  // transposed: [col][k]
            ATl[j * 128 + k] = f2bf(acc - bf2f(hh));
        }
        return;
    }
    const int j = t;
    if (j < 16) {
        float a = 0.f;
        for (int m = 0; m < 64; ++m) a = fmaf(b1[m], w2l[m * 16 + j], a);
        cbuf[j] = a;
    } else if (j < 32) {
        const int jj = j - 16;
        float a = 0.f;
        for (int m = 0; m < 64; ++m) a = fmaf(b1[m], w2r[m * 16 + jj], a);
        cbuf[j] = a;
    } else if (j < 48) {
        const int k = j - 32;
        float a = 0.f;
        for (int m = 0; m < 8; ++m) a = fmaf(fc1w[k * 8 + m], fc2w[m], a);
        cbuf[j] = a;
    } else if (j == 48) {
        float a = fc2b[0];
        for (int m = 0; m < 8; ++m) a = fmaf(fc1b[m], fc2w[m], a);
        cbuf[48] = a;
    }
}

// single 256-thread block: per-bucket prefix over ABLK + block-scan of totals
__global__ __launch_bounds__(256) void scan_all(int* __restrict__ mat,
    int* __restrict__ bbase)
{
    __shared__ int s[256];
    const int t = threadIdx.x;
    int run = 0;
    if (t < NB) {
        int* col = mat + (size_t)t * ABLK;
        for (int a = 0; a < ABLK; ++a) { const int v = col[a]; col[a] = run; run += v; }
    }
    s[t] = (t < NB) ? run : 0;
    __syncthreads();
    for (int off = 1; off < 256; off <<= 1) {
        const int u = (t >= off) ? s[t - off] : 0;
        __syncthreads();
        s[t] += u;
        __syncthreads();
    }
    if (t < NB) bbase[t] = s[t] - run;         // exclusive
    if (t == NB - 1) bbase[NB] = s[t];         // == NE
}

// ============ K3: fused scatter (blocks 0..127) + MFMA gemm (128..) ============
__global__ __launch_bounds__(512) void fused1(const int* __restrict__ src,
    const int* __restrict__ dst, const int* __restrict__ mat,
    const int* __restrict__ bbase, unsigned* __restrict__ part,
    const float* __restrict__ x, const unsigned short* __restrict__ ATh,
    const unsigned short* __restrict__ ATl, signed char* __restrict__ p8,
    float* __restrict__ pscale, __half* __restrict__ qh)
{
    __shared__ unsigned short sAh[64 * LDST];
    __shared__ unsigned short sAl[64 * LDST];
    __shared__ int cur[NB];
    const int tid = threadIdx.x;

    if (blockIdx.x < ABLK) {
        // ---- partA_scatter (4x unrolled: 4 independent latency chains) ----
        const int a = blockIdx.x;
        for (int i = tid; i < NB; i += 512)
            cur[i] = mat[(size_t)i * ABLK + a] + bbase[i];
        __syncthreads();
        const int beg = a * EPB;
        const int end = (beg + EPB < NE) ? beg + EPB : NE;
        int e = beg + tid;
        for (; e + 3 * 512 < end; e += 4 * 512) {
            const int s0 = src[e],          d0 = dst[e];
            const int s1 = src[e + 512],    d1 = dst[e + 512];
            const int s2 = src[e + 1024],   d2 = dst[e + 1024];
            const int s3 = src[e + 1536],   d3 = dst[e + 1536];
            const int p0 = atomicAdd(&cur[d0 >> BSH], 1);
            const int p1 = atomicAdd(&cur[d1 >> BSH], 1);
            const int p2 = atomicAdd(&cur[d2 >> BSH], 1);
            const int p3 = atomicAdd(&cur[d3 >> BSH], 1);
            part[p0] = ((unsigned)s0 << BSH) | (unsigned)(d0 & (BKN - 1));
            part[p1] = ((unsigned)s1 << BSH) | (unsigned)(d1 & (BKN - 1));
            part[p2] = ((unsigned)s2 << BSH) | (unsigned)(d2 & (BKN - 1));
            part[p3] = ((unsigned)s3 << BSH) | (unsigned)(d3 & (BKN - 1));
        }
        for (; e < end; e += 512) {
            const int s = src[e], d = dst[e];
            const int pos = atomicAdd(&cur[d >> BSH], 1);
            part[pos] = ((unsigned)s << BSH) | (unsigned)(d & (BKN - 1));
        }
        return;
    }

    // ---- gemm: 2 tiles per block, shared A staging ----
    for (int i = tid; i < 1024; i += 512) {
        const int row = i >> 4, ch = i & 15;
        const uint4 vh = *(const uint4*)(ATh + row * 128 + ch * 8);
        const uint4 vl = *(const uint4*)(ATl + row * 128 + ch * 8);
        *(uint4*)(sAh + row * LDST + ch * 8) = vh;
        *(uint4*)(sAl + row * LDST + ch * 8) = vl;
    }
    __syncthreads();

    const int wave8 = tid >> 6;            // 0..7
    const int tile = (blockIdx.x - ABLK) * 2 + (wave8 >> 2);
    const int wave = wave8 & 3;            // 0..3 within tile-group
    const int lane = tid & 63;
    const int lr = lane & 15;
    const int lg = lane >> 4;

    bf16x8 bh[4][4], bl[4][4];
#pragma unroll
    for (int ct = 0; ct < 4; ++ct) {
        const int col = ct * 16 + lr;
#pragma unroll
        for (int ks = 0; ks < 4; ++ks) {
            const int k0 = ks * 32 + lg * 8;
            bh[ct][ks] = *(const bf16x8*)(sAh + col * LDST + k0);
            bl[ct][ks] = *(const bf16x8*)(sAl + col * LDST + k0);
        }
    }

    if (tile >= GEMMB) return;
    const int tilebase = tile * 64;
    const int xrowidx = tilebase + wave * 16 + lr;
    const float* xrow = x + (size_t)(xrowidx < NN ? xrowidx : NN - 1) * 128;

    f32x4 acc[4] = {f32x4{0,0,0,0}, f32x4{0,0,0,0}, f32x4{0,0,0,0}, f32x4{0,0,0,0}};
#pragma unroll
    for (int ks = 0; ks < 4; ++ks) {
        const int k0 = ks * 32 + lg * 8;
        const float4 v0 = *(const float4*)(xrow + k0);
        const float4 v1 = *(const float4*)(xrow + k0 + 4);
        const float vv[8] = {v0.x, v0.y, v0.z, v0.w, v1.x, v1.y, v1.z, v1.w};
        bf16x8 xh, xl;
#pragma unroll
        for (int j = 0; j < 8; ++j) {
            const unsigned short h = f2bf(vv[j]);
            xh[j] = (short)h;
            xl[j] = (short)f2bf(vv[j] - bf2f(h));
        }
#pragma unroll
        for (int ct = 0; ct < 4; ++ct) {
            acc[ct] = __builtin_amdgcn_mfma_f32_16x16x32_bf16(xh, bh[ct][ks], acc[ct], 0, 0, 0);
            acc[ct] = __builtin_amdgcn_mfma_f32_16x16x32_bf16(xh, bl[ct][ks], acc[ct], 0, 0, 0);
            acc[ct] = __builtin_amdgcn_mfma_f32_16x16x32_bf16(xl, bh[ct][ks], acc[ct], 0, 0, 0);
        }
    }

#pragma unroll
    for (int rg = 0; rg < 4; ++rg) {
        float m = fmaxf(fabsf(acc[0][rg]), fabsf(acc[1][rg]));
#pragma unroll
        for (int d = 1; d < 16; d <<= 1) m = fmaxf(m, __shfl_xor(m, d, 64));
        m = fmaxf(m, 1e-20f);
        const float scl = m * (1.0f / 127.0f);
        const float inv = 127.0f / m;
        const int nrow = tilebase + wave * 16 + lg * 4 + rg;
        if (nrow < NN) {
            const int q0 = __float2int_rn(acc[0][rg] * inv);
            const int q1 = __float2int_rn(acc[1][rg] * inv);
            p8[(size_t)nrow * 32 + lr]      = (signed char)q0;
            p8[(size_t)nrow * 32 + 16 + lr] = (signed char)q1;
            if (lr == 0) pscale[nrow] = scl;
            qh[(size_t)nrow * 32 + lr]      = __float2half(acc[2][rg]);
            qh[(size_t)nrow * 32 + 16 + lr] = __float2half(acc[3][rg]);
        }
    }
}

__global__ __launch_bounds__(512) void partB_build(const unsigned* __restrict__ part,
    const int* __restrict__ bbase, int* __restrict__ rowptr, int* __restrict__ cols)
{
    __shared__ int h[BKN];
    __shared__ int cur[BKN];
    __shared__ int wsum[8];
    const int b = blockIdx.x;
    const int t = threadIdx.x;
    const int beg = bbase[b], end = bbase[b + 1];
    h[t] = 0;
    __syncthreads();
    {
        int e = beg + t;
        for (; e + 3 * 512 < end; e += 4 * 512) {
            const unsigned w0 = part[e], w1 = part[e + 512];
            const unsigned w2 = part[e + 1024], w3 = part[e + 1536];
            atomicAdd(&h[w0 & (BKN - 1u)], 1);
            atomicAdd(&h[w1 & (BKN - 1u)], 1);
            atomicAdd(&h[w2 & (BKN - 1u)], 1);
            atomicAdd(&h[w3 & (BKN - 1u)], 1);
        }
        for (; e < end; e += 512)
            atomicAdd(&h[part[e] & (BKN - 1u)], 1);
    }
    __syncthreads();
    const int v = h[t];
    int inc = v;
#pragma unroll
    for (int d = 1; d < 64; d <<= 1) {
        const int u = __shfl_up(inc, d, 64);
        if ((t & 63) >= d) inc += u;
    }
    if ((t & 63) == 63) wsum[t >> 6] = inc;
    __syncthreads();
    int woff = 0;
    for (int w = 0; w < (t >> 6); ++w) woff += wsum[w];
    const int excl = inc + woff - v;
    cur[t] = excl;
    const int node = b * BKN + t;
    if (node < NN) rowptr[node] = beg + excl;
    if (b == NB - 1 && t == 0) rowptr[NN] = NE;
    __syncthreads();
    {
        int e = beg + t;
        for (; e + 3 * 512 < end; e += 4 * 512) {
            const unsigned w0 = part[e], w1 = part[e + 512];
            const unsigned w2 = part[e + 1024], w3 = part[e + 1536];
            const int p0 = atomicAdd(&cur[w0 & (BKN - 1u)], 1);
            const int p1 = atomicAdd(&cur[w1 & (BKN - 1u)], 1);
            const int p2 = atomicAdd(&cur[w2 & (BKN - 1u)], 1);
            const int p3 = atomicAdd(&cur[w3 & (BKN - 1u)], 1);
            cols[beg + p0] = (int)(w0 >> BSH);
            cols[beg + p1] = (int)(w1 >> BSH);
            cols[beg + p2] = (int)(w2 >> BSH);
            cols[beg + p3] = (int)(w3 >> BSH);
        }
        for (; e < end; e += 512) {
            const unsigned w = part[e];
            const int pos = atomicAdd(&cur[w & (BKN - 1u)], 1);
            cols[beg + pos] = (int)(w >> BSH);
        }
    }
}

// ============ aggregation via CSR: register-cached cols + shfl ============
// layer 1: 32 lanes per node; lane caches cols[beg+lane] (deg<=32 covered);
// batch of 8 edge-slots gets src via shfl -> gathers issue without cols chain.
__global__ __launch_bounds__(256) void agg1_csr(const int* __restrict__ rowptr,
    const int* __restrict__ cols, const signed char* __restrict__ p8,
    const float* __restrict__ pscale, const __half* __restrict__ qh,
    const float* __restrict__ cbuf, __half* __restrict__ g, __half* __restrict__ r)
{
    const int node = blockIdx.x * 8 + (threadIdx.x >> 5);
    if (node >= NN) return;
    const int lane = threadIdx.x & 31;
    const int es = lane >> 2;      // edge slot 0..7
    const int k  = lane & 3;       // uint2 index 0..3 (feats 8k..8k+7)
    const int beg = rowptr[node], end = rowptr[node + 1];
    const int deg = end - beg;
    const int grpbase = threadIdx.x & 32;   // group offset within the 64-lane wave
    const int myc = (lane < deg) ? cols[beg + lane] : 0;
    const uint2* p64 = (const uint2*)p8;
    float a0 = 0.f, a1 = 0.f, a2 = 0.f, a3 = 0.f;
    float a4 = 0.f, a5 = 0.f, a6 = 0.f, a7 = 0.f;
#pragma unroll 2
    for (int base = 0; base < deg; base += 8) {
        const int idx = base + es;
        const bool valid = idx < deg;
        int s;
        if (idx < 32) s = __shfl(myc, grpbase + idx, 64);
        else          s = cols[beg + (valid ? idx : deg - 1)];
        const float scl = valid ? pscale[s] : 0.f;
        const uint2 w = p64[(size_t)s * 4 + k];
        a0 = fmaf((float)(signed char)(w.x & 0xffu), scl, a0);
        a1 = fmaf((float)(signed char)((w.x >> 8) & 0xffu), scl, a1);
        a2 = fmaf((float)(signed char)((w.x >> 16) & 0xffu), scl, a2);
        a3 = fmaf((float)(signed char)(w.x >> 24), scl, a3);
        a4 = fmaf((float)(signed char)(w.y & 0xffu), scl, a4);
        a5 = fmaf((float)(signed char)((w.y >> 8) & 0xffu), scl, a5);
        a6 = fmaf((float)(signed char)((w.y >> 16) & 0xffu), scl, a6);
        a7 = fmaf((float)(signed char)(w.y >> 24), scl, a7);
    }
#pragma unroll
    for (int d = 4; d <= 16; d <<= 1) {
        a0 += __shfl_xor(a0, d, 64); a1 += __shfl_xor(a1, d, 64);
        a2 += __shfl_xor(a2, d, 64); a3 += __shfl_xor(a3, d, 64);
        a4 += __shfl_xor(a4, d, 64); a5 += __shfl_xor(a5, d, 64);
        a6 += __shfl_xor(a6, d, 64); a7 += __shfl_xor(a7, d, 64);
    }
    if (es == 0) {
        // lane k holds feats 8k..8k+7
        const float dg = (float)deg;
        const float inv = 1.0f / fmaxf(dg, 1.0f);
        const uint4 qw = *(const uint4*)(qh + (size_t)node * 32 + 8 * k);
        const float2 q0 = unpackh2(qw.x), q1 = unpackh2(qw.y);
        const float2 q2 = unpackh2(qw.z), q3 = unpackh2(qw.w);
        const float4 cb0 = *(const float4*)(cbuf + 8 * k);
        const float4 cb1 = *(const float4*)(cbuf + 8 * k + 4);
        const float v0 = fmaf(a0, inv, q0.x + cb0.x);
        const float v1 = fmaf(a1, inv, q0.y + cb0.y);
        const float v2 = fmaf(a2, inv, q1.x + cb0.z);
        const float v3 = fmaf(a3, inv, q1.y + cb0.w);
        const float v4 = fmaf(a4, inv, q2.x + cb1.x);
        const float v5 = fmaf(a5, inv, q2.y + cb1.y);
        const float v6 = fmaf(a6, inv, q3.x + cb1.z);
        const float v7 = fmaf(a7, inv, q3.y + cb1.w);
        uint4 ow;
        ow.x = __builtin_bit_cast(unsigned, __floats2half2_rn(v0, v1));
        ow.y = __builtin_bit_cast(unsigned, __floats2half2_rn(v2, v3));
        ow.z = __builtin_bit_cast(unsigned, __floats2half2_rn(v4, v5));
        ow.w = __builtin_bit_cast(unsigned, __floats2half2_rn(v6, v7));
        if (k < 2) *(uint4*)(g + (size_t)node * 16 + 8 * k) = ow;
        else       *(uint4*)(r + (size_t)node * 16 + 8 * (k - 2)) = ow;
    }
}

__global__ __launch_bounds__(256) void agg2_csr(const int* __restrict__ rowptr,
    const int* __restrict__ cols, const __half* __restrict__ g,
    const __half* __restrict__ r, const float* __restrict__ b2,
    __half* __restrict__ h2)
{
    const int node = blockIdx.x * 8 + (threadIdx.x >> 5);
    if (node >= NN) return;
    const int lane = threadIdx.x & 31;
    const int es = lane >> 2;
    const int k  = lane & 3;       // feats 4k..4k+3
    const int beg = rowptr[node], end = rowptr[node + 1];
    const int deg = end - beg;
    const int grpbase = threadIdx.x & 32;
    const int myc = (lane < deg) ? cols[beg + lane] : 0;
    const uint2* g64 = (const uint2*)g;
    float a0 = 0.f, a1 = 0.f, a2 = 0.f, a3 = 0.f;
#pragma unroll 2
    for (int base = 0; base < deg; base += 8) {
        const int idx = base + es;
        const bool valid = idx < deg;
        int s;
        if (idx < 32) s = __shfl(myc, grpbase + idx, 64);
        else          s = cols[beg + (valid ? idx : deg - 1)];
        const float m = valid ? 1.0f : 0.0f;
        const uint2 w = g64[(size_t)s * 4 + k];
        const float2 v0 = unpackh2(w.x);
        const float2 v1 = unpackh2(w.y);
        a0 = fmaf(v0.x, m, a0);
        a1 = fmaf(v0.y, m, a1);
        a2 = fmaf(v1.x, m, a2);
        a3 = fmaf(v1.y, m, a3);
    }
#pragma unroll
    for (int d = 4; d <= 16; d <<= 1) {
        a0 += __shfl_xor(a0, d, 64); a1 += __shfl_xor(a1, d, 64);
        a2 += __shfl_xor(a2, d, 64); a3 += __shfl_xor(a3, d, 64);
    }
    if (es == 0) {
        const float dg = (float)deg;
        const float inv = 1.0f / fmaxf(dg, 1.0f);
        const uint2 rw = ((const uint2*)r)[(size_t)node * 4 + k];
        const float2 r0 = unpackh2(rw.x), r1 = unpackh2(rw.y);
        const float4 bb = *(const float4*)(b2 + 4 * k);
        const float v0 = fmaf(a0, inv, r0.x + bb.x);
        const float v1 = fmaf(a1, inv, r0.y + bb.y);
        const float v2 = fmaf(a2, inv, r1.x + bb.z);
        const float v3 = fmaf(a3, inv, r1.y + bb.w);
        uint2 ow;
        ow.x = __builtin_bit_cast(unsigned, __floats2half2_rn(v0, v1));
        ow.y = __builtin_bit_cast(unsigned, __floats2half2_rn(v2, v3));
        ((uint2*)h2)[(size_t)node * 4 + k] = ow;
    }
}

// ---- out = sigmoid( sum_k h2[s][k]*h2[d][k]*v[k] + c ); 4 edges per thread
__global__ __launch_bounds__(256) void edge_mlp(const int* __restrict__ src,
    const int* __restrict__ dst, const __half* __restrict__ h2,
    const float* __restrict__ cbuf, float* __restrict__ out)
{
    __shared__ float sv[17];
    if (threadIdx.x < 16) sv[threadIdx.x] = cbuf[32 + threadIdx.x];
    if (threadIdx.x == 16) sv[16] = cbuf[48];
    __syncthreads();
    const int ebase = blockIdx.x * 1024 + threadIdx.x;
#pragma unroll
    for (int u = 0; u < 4; ++u) {
        const int e = ebase + u * 256;
        if (e >= NE) return;
        const int s = src[e], d = dst[e];
        const uint4* hs = (const uint4*)(h2 + (size_t)s * 16);
        const uint4* hd = (const uint4*)(h2 + (size_t)d * 16);
        const uint4 a0 = hs[0], a1 = hs[1];
        const uint4 b0 = hd[0], b1 = hd[1];
        const unsigned aw[8] = {a0.x, a0.y, a0.z, a0.w, a1.x, a1.y, a1.z, a1.w};
        const unsigned bw[8] = {b0.x, b0.y, b0.z, b0.w, b1.x, b1.y, b1.z, b1.w};
        float acc = sv[16];
#pragma unroll
        for (int qq = 0; qq < 8; ++qq) {
            const float2 a = unpackh2(aw[qq]);
            const float2 b = unpackh2(bw[qq]);
            acc = fmaf(a.x * b.x, sv[qq * 2 + 0], acc);
            acc = fmaf(a.y * b.y, sv[qq * 2 + 1], acc);
        }
        out[e] = 1.0f / (1.0f + __expf(-acc));
    }
}

extern "C" void kernel_launch(void* const* d_in, const int* in_sizes, int n_in,
                              void* d_out, int out_size, void* d_ws, size_t ws_size,
                              hipStream_t stream)
{
    const float* x    = (const float*)d_in[0];
    const int*   ei   = (const int*)d_in[1];
    const float* w1l  = (const float*)d_in[2];
    const float* w1r  = (const float*)d_in[3];
    const float* b1   = (const float*)d_in[4];
    const float* w2l  = (const float*)d_in[5];
    const float* w2r  = (const float*)d_in[6];
    const float* b2   = (const float*)d_in[7];
    const float* fc1w = (const float*)d_in[8];
    const float* fc1b = (const float*)d_in[9];
    const float* fc2w = (const float*)d_in[10];
    const float* fc2b = (const float*)d_in[11];
    float* out = (float*)d_out;

    const int* src = ei;
    const int* dst = ei + NE;

    // workspace layout (int units)
    int* W = (int*)d_ws;
    size_t o = 0;
#define ALIGN16() o = (o + 15) & ~(size_t)15
    int* mat    = W + o; o += (size_t)NB * ABLK; ALIGN16();
    int* bbase  = W + o; o += NB + 1;            ALIGN16();
    int* rowptr = W + o; o += NN + 1;            ALIGN16();
    unsigned* part = (unsigned*)(W + o); o += NE; ALIGN16();
    int* cols   = W + o; o += NE;                ALIGN16();
    unsigned short* ATh = (unsigned short*)(W + o); o += 4096; ALIGN16();
    unsigned short* ATl = (unsigned short*)(W + o); o += 4096; ALIGN16();
    float* cbuf = (float*)(W + o); o += 64;      ALIGN16();
    signed char* p8 = (signed char*)(W + o); o += (size_t)NN * 8;  ALIGN16();
    float* pscale   = (float*)(W + o); o += NN;  ALIGN16();
    __half* qh  = (__half*)(W + o); o += (size_t)NN * 16; ALIGN16();
    __half* g   = (__half*)(W + o); o += (size_t)NN * 8;  ALIGN16();
    __half* r   = (__half*)(W + o); o += (size_t)NN * 8;  ALIGN16();
    __half* h2  = (__half*)(W + o); o += (size_t)NN * 8;  ALIGN16();

    // K1: count || precomp
    fused0<<<ABLK + 129, 256, 0, stream>>>(dst, w1l, w1r, w2l, w2r, b1,
                                           fc1w, fc1b, fc2w, fc2b, mat, ATh, ATl, cbuf);
    // K2: scan
    scan_all<<<1, 256, 0, stream>>>(mat, bbase);
    // K3: scatter || gemm (512 threads; gemm 2 tiles/block, LDS-staged)
    fused1<<<ABLK + GBLK, 512, 0, stream>>>(src, dst, mat, bbase, part,
                                            x, ATh, ATl, p8, pscale, qh);
    // K4: per-bucket CSR
    partB_build<<<NB, 512, 0, stream>>>(part, bbase, rowptr, cols);
    // K5/K6: aggregations (reg-cached cols, shfl-distributed src indices)
    agg1_csr<<<(NN + 7) / 8, 256, 0, stream>>>(rowptr, cols, p8, pscale, qh, cbuf, g, r);
    agg2_csr<<<(NN + 7) / 8, 256, 0, stream>>>(rowptr, cols, g, r, b2, h2);
    // K7: head (4 edges/thread)
    edge_mlp<<<(NE + 1023) / 1024, 256, 0, stream>>>(src, dst, h2, cbuf, out);
}

// Round 22
// 122.142 us; speedup vs baseline: 1.2779x; 1.0329x over previous
//
#include <hip/hip_runtime.h>
#include <hip/hip_fp16.h>
#include <math.h>

#define NN 100000
#define NE 1600000

#define BSH  8          // bucket = dst >> 8
#define BKN  256        // nodes per bucket
#define NB   391        // ceil(NN/256)
#define ABLK 128        // partition blocks (EPB/NB ~ 32-entry runs = 128B)
#define EPB  ((NE + ABLK - 1) / ABLK)   // 12500 edges per partition block
#define GEMMB ((NN + 63) / 64)          // 1563 gemm tiles
#define GBLK ((GEMMB + 1) / 2)          // 782 gemm blocks (2 tiles each)
#define LDST 136

typedef __attribute__((ext_vector_type(8))) short bf16x8;
typedef __attribute__((ext_vector_type(4))) float f32x4;

__device__ __forceinline__ unsigned short f2bf(float f) {
    unsigned u = __builtin_bit_cast(unsigned, f);
    u += 0x7fffu + ((u >> 16) & 1u);           // RNE
    return (unsigned short)(u >> 16);
}
__device__ __forceinline__ float bf2f(unsigned short h) {
    unsigned u = ((unsigned)h) << 16;
    return __builtin_bit_cast(float, u);
}
__device__ __forceinline__ float2 unpackh2(unsigned w) {
    const __half2 h = __builtin_bit_cast(__half2, w);
    return __half22float2(h);
}

// ============ K1: fused count (blocks 0..127) + precomp (128..256) ============
__global__ __launch_bounds__(256) void fused0(const int* __restrict__ dst,
    const float* __restrict__ w1l, const float* __restrict__ w1r,
    const float* __restrict__ w2l, const float* __restrict__ w2r,
    const float* __restrict__ b1, const float* __restrict__ fc1w,
    const float* __restrict__ fc1b, const float* __restrict__ fc2w,
    const float* __restrict__ fc2b, int* __restrict__ mat,
    unsigned short* __restrict__ ATh, unsigned short* __restrict__ ATl,
    float* __restrict__ cbuf)
{
    __shared__ int h[NB];
    __shared__ float sl[64], sr[64];
    const int t = threadIdx.x;
    if (blockIdx.x < ABLK) {
        for (int i = t; i < NB; i += 256) h[i] = 0;
        __syncthreads();
        const int a = blockIdx.x;
        const int beg = a * EPB;
        const int end = (beg + EPB < NE) ? beg + EPB : NE;
        int e = beg + t;
        for (; e + 3 * 256 < end; e += 4 * 256) {
            const int d0 = dst[e], d1 = dst[e + 256], d2 = dst[e + 512], d3 = dst[e + 768];
            atomicAdd(&h[d0 >> BSH], 1);
            atomicAdd(&h[d1 >> BSH], 1);
            atomicAdd(&h[d2 >> BSH], 1);
            atomicAdd(&h[d3 >> BSH], 1);
        }
        for (; e < end; e += 256)
            atomicAdd(&h[dst[e] >> BSH], 1);
        __syncthreads();
        for (int i = t; i < NB; i += 256) mat[(size_t)i * ABLK + a] = h[i];
        return;
    }
    if (blockIdx.x < ABLK + 128) {
        const int k = blockIdx.x - ABLK;
        const int j = t;
        if (j < 64) { sl[j] = w1l[k * 64 + j]; sr[j] = w1r[k * 64 + j]; }
        __syncthreads();
        if (j < 64) {
            const int sel = j >> 4, jj = j & 15;
            const float* row = (sel < 2) ? sl : sr;
            const float* w2  = (sel & 1) ? w2r : w2l;
            float acc = 0.f;
#pragma unroll
            for (int m = 0; m < 64; ++m) acc = fmaf(row[m], w2[m * 16 + jj], acc);
            const unsigned short hh = f2bf(acc);
            ATh[j * 128 + k] = hh;                  // transposed: [col][k]
            ATl[j * 128 + k] = f2bf(acc - bf2f(hh));
        }
        return;
    }
    const int j = t;
    if (j < 16) {
        float a = 0.f;
        for (int m = 0; m < 64; ++m) a = fmaf(b1[m], w2l[m * 16 + j], a);
        cbuf[j] = a;
    } else if (j < 32) {
        const int jj = j - 16;
        float a = 0.f;
        for (int m = 0; m < 64; ++m) a = fmaf(b1[m], w2r[m * 16 + jj], a);
        cbuf[j] = a;
    } else if (j < 48) {
        const int k = j - 32;
        float a = 0.f;
        for (int m = 0; m < 8; ++m) a = fmaf(fc1w[k * 8 + m], fc2w[m], a);
        cbuf[j] = a;
    } else if (j == 48) {
        float a = fc2b[0];
        for (int m = 0; m < 8; ++m) a = fmaf(fc1b[m], fc2w[m], a);
        cbuf[48] = a;
    }
}

// ============ K2: fused scatter+inline-scan (blocks 0..127) + gemm (128..) ======
__global__ __launch_bounds__(512) void fused1(const int* __restrict__ src,
    const int* __restrict__ dst, const int* __restrict__ mat,
    int* __restrict__ bbase, unsigned* __restrict__ part,
    const float* __restrict__ x, const unsigned short* __restrict__ ATh,
    const unsigned short* __restrict__ ATl, signed char* __restrict__ p8,
    float* __restrict__ pscale, __half* __restrict__ qh)
{
    __shared__ unsigned short sAh[64 * LDST];
    __shared__ unsigned short sAl[64 * LDST];
    __shared__ int cur[NB];
    __shared__ int tot[NB];
    __shared__ int sarr[512];
    const int tid = threadIdx.x;

    if (blockIdx.x < ABLK) {
        // ---- inline scan: bucket totals + our block's within-bucket prefix ----
        const int a = blockIdx.x;
        for (int i = tid; i < NB; i += 512) {
            const int* col = mat + (size_t)i * ABLK;
            int run = 0, mypre = 0;
            for (int a2 = 0; a2 < ABLK; ++a2) {
                const int v = col[a2];
                mypre += (a2 < a) ? v : 0;
                run += v;
            }
            tot[i] = run;
            cur[i] = mypre;
        }
        __syncthreads();
        const int myrun = (tid < NB) ? tot[tid] : 0;
        sarr[tid] = myrun;
        __syncthreads();
        for (int off = 1; off < 512; off <<= 1) {
            const int u = (tid >= off) ? sarr[tid - off] : 0;
            __syncthreads();
            sarr[tid] += u;
            __syncthreads();
        }
        if (tid < NB) {
            const int base = sarr[tid] - myrun;   // exclusive bucket base
            cur[tid] += base;
            if (a == 0) bbase[tid] = base;        // persist for partB
        }
        if (a == 0 && tid == NB - 1) bbase[NB] = sarr[tid];
        __syncthreads();

        // ---- scatter (4x unrolled) ----
        const int beg = a * EPB;
        const int end = (beg + EPB < NE) ? beg + EPB : NE;
        int e = beg + tid;
        for (; e + 3 * 512 < end; e += 4 * 512) {
            const int s0 = src[e],          d0 = dst[e];
            const int s1 = src[e + 512],    d1 = dst[e + 512];
            const int s2 = src[e + 1024],   d2 = dst[e + 1024];
            const int s3 = src[e + 1536],   d3 = dst[e + 1536];
            const int p0 = atomicAdd(&cur[d0 >> BSH], 1);
            const int p1 = atomicAdd(&cur[d1 >> BSH], 1);
            const int p2 = atomicAdd(&cur[d2 >> BSH], 1);
            const int p3 = atomicAdd(&cur[d3 >> BSH], 1);
            part[p0] = ((unsigned)s0 << BSH) | (unsigned)(d0 & (BKN - 1));
            part[p1] = ((unsigned)s1 << BSH) | (unsigned)(d1 & (BKN - 1));
            part[p2] = ((unsigned)s2 << BSH) | (unsigned)(d2 & (BKN - 1));
            part[p3] = ((unsigned)s3 << BSH) | (unsigned)(d3 & (BKN - 1));
        }
        for (; e < end; e += 512) {
            const int s = src[e], d = dst[e];
            const int pos = atomicAdd(&cur[d >> BSH], 1);
            part[pos] = ((unsigned)s << BSH) | (unsigned)(d & (BKN - 1));
        }
        return;
    }

    // ---- gemm: 2 tiles per block, shared A staging ----
    for (int i = tid; i < 1024; i += 512) {
        const int row = i >> 4, ch = i & 15;
        const uint4 vh = *(const uint4*)(ATh + row * 128 + ch * 8);
        const uint4 vl = *(const uint4*)(ATl + row * 128 + ch * 8);
        *(uint4*)(sAh + row * LDST + ch * 8) = vh;
        *(uint4*)(sAl + row * LDST + ch * 8) = vl;
    }
    __syncthreads();

    const int wave8 = tid >> 6;            // 0..7
    const int tile = (blockIdx.x - ABLK) * 2 + (wave8 >> 2);
    const int wave = wave8 & 3;            // 0..3 within tile-group
    const int lane = tid & 63;
    const int lr = lane & 15;
    const int lg = lane >> 4;

    bf16x8 bh[4][4], bl[4][4];
#pragma unroll
    for (int ct = 0; ct < 4; ++ct) {
        const int col = ct * 16 + lr;
#pragma unroll
        for (int ks = 0; ks < 4; ++ks) {
            const int k0 = ks * 32 + lg * 8;
            bh[ct][ks] = *(const bf16x8*)(sAh + col * LDST + k0);
            bl[ct][ks] = *(const bf16x8*)(sAl + col * LDST + k0);
        }
    }

    if (tile >= GEMMB) return;
    const int tilebase = tile * 64;
    const int xrowidx = tilebase + wave * 16 + lr;
    const float* xrow = x + (size_t)(xrowidx < NN ? xrowidx : NN - 1) * 128;

    f32x4 acc[4] = {f32x4{0,0,0,0}, f32x4{0,0,0,0}, f32x4{0,0,0,0}, f32x4{0,0,0,0}};
#pragma unroll
    for (int ks = 0; ks < 4; ++ks) {
        const int k0 = ks * 32 + lg * 8;
        const float4 v0 = *(const float4*)(xrow + k0);
        const float4 v1 = *(const float4*)(xrow + k0 + 4);
        const float vv[8] = {v0.x, v0.y, v0.z, v0.w, v1.x, v1.y, v1.z, v1.w};
        bf16x8 xh, xl;
#pragma unroll
        for (int j = 0; j < 8; ++j) {
            const unsigned short h = f2bf(vv[j]);
            xh[j] = (short)h;
            xl[j] = (short)f2bf(vv[j] - bf2f(h));
        }
#pragma unroll
        for (int ct = 0; ct < 4; ++ct) {
            acc[ct] = __builtin_amdgcn_mfma_f32_16x16x32_bf16(xh, bh[ct][ks], acc[ct], 0, 0, 0);
            acc[ct] = __builtin_amdgcn_mfma_f32_16x16x32_bf16(xh, bl[ct][ks], acc[ct], 0, 0, 0);
            acc[ct] = __builtin_amdgcn_mfma_f32_16x16x32_bf16(xl, bh[ct][ks], acc[ct], 0, 0, 0);
        }
    }

#pragma unroll
    for (int rg = 0; rg < 4; ++rg) {
        float m = fmaxf(fabsf(acc[0][rg]), fabsf(acc[1][rg]));
#pragma unroll
        for (int d = 1; d < 16; d <<= 1) m = fmaxf(m, __shfl_xor(m, d, 64));
        m = fmaxf(m, 1e-20f);
        const float scl = m * (1.0f / 127.0f);
        const float inv = 127.0f / m;
        const int nrow = tilebase + wave * 16 + lg * 4 + rg;
        if (nrow < NN) {
            const int q0 = __float2int_rn(acc[0][rg] * inv);
            const int q1 = __float2int_rn(acc[1][rg] * inv);
            p8[(size_t)nrow * 32 + lr]      = (signed char)q0;
            p8[(size_t)nrow * 32 + 16 + lr] = (signed char)q1;
            if (lr == 0) pscale[nrow] = scl;
            qh[(size_t)nrow * 32 + lr]      = __float2half(acc[2][rg]);
            qh[(size_t)nrow * 32 + 16 + lr] = __float2half(acc[3][rg]);
        }
    }
}

// ============ K3: per-bucket CSR build (391 blocks) ============
__global__ __launch_bounds__(512) void partB_build(const unsigned* __restrict__ part,
    const int* __restrict__ bbase, int* __restrict__ rowptr, int* __restrict__ cols)
{
    __shared__ int h[BKN];
    __shared__ int cur[BKN];
    __shared__ int wsum[8];
    const int b = blockIdx.x;
    const int t = threadIdx.x;
    const int beg = bbase[b], end = bbase[b + 1];
    if (t < BKN) h[t] = 0;
    __syncthreads();
    {
        int e = beg + t;
        for (; e + 3 * 512 < end; e += 4 * 512) {
            const unsigned w0 = part[e], w1 = part[e + 512];
            const unsigned w2 = part[e + 1024], w3 = part[e + 1536];
            atomicAdd(&h[w0 & (BKN - 1u)], 1);
            atomicAdd(&h[w1 & (BKN - 1u)], 1);
            atomicAdd(&h[w2 & (BKN - 1u)], 1);
            atomicAdd(&h[w3 & (BKN - 1u)], 1);
        }
        for (; e < end; e += 512)
            atomicAdd(&h[part[e] & (BKN - 1u)], 1);
    }
    __syncthreads();
    const int v = (t < BKN) ? h[t] : 0;
    int inc = v;
#pragma unroll
    for (int d = 1; d < 64; d <<= 1) {
        const int u = __shfl_up(inc, d, 64);
        if ((t & 63) >= d) inc += u;
    }
    if ((t & 63) == 63) wsum[t >> 6] = inc;
    __syncthreads();
    int woff = 0;
    for (int w = 0; w < (t >> 6); ++w) woff += wsum[w];
    const int excl = inc + woff - v;
    if (t < BKN) {
        cur[t] = excl;
        const int node = b * BKN + t;
        if (node < NN) rowptr[node] = beg + excl;
    }
    if (b == NB - 1 && t == 0) rowptr[NN] = NE;
    __syncthreads();
    {
        int e = beg + t;
        for (; e + 3 * 512 < end; e += 4 * 512) {
            const unsigned w0 = part[e], w1 = part[e + 512];
            const unsigned w2 = part[e + 1024], w3 = part[e + 1536];
            const int p0 = atomicAdd(&cur[w0 & (BKN - 1u)], 1);
            const int p1 = atomicAdd(&cur[w1 & (BKN - 1u)], 1);
            const int p2 = atomicAdd(&cur[w2 & (BKN - 1u)], 1);
            const int p3 = atomicAdd(&cur[w3 & (BKN - 1u)], 1);
            cols[beg + p0] = (int)(w0 >> BSH);
            cols[beg + p1] = (int)(w1 >> BSH);
            cols[beg + p2] = (int)(w2 >> BSH);
            cols[beg + p3] = (int)(w3 >> BSH);
        }
        for (; e < end; e += 512) {
            const unsigned w = part[e];
            const int pos = atomicAdd(&cur[w & (BKN - 1u)], 1);
            cols[beg + pos] = (int)(w >> BSH);
        }
    }
}

// ============ aggregation via CSR: register-cached cols + shfl ============
__global__ __launch_bounds__(256) void agg1_csr(const int* __restrict__ rowptr,
    const int* __restrict__ cols, const signed char* __restrict__ p8,
    const float* __restrict__ pscale, const __half* __restrict__ qh,
    const float* __restrict__ cbuf, __half* __restrict__ g, __half* __restrict__ r)
{
    const int node = blockIdx.x * 8 + (threadIdx.x >> 5);
    if (node >= NN) return;
    const int lane = threadIdx.x & 31;
    const int es = lane >> 2;      // edge slot 0..7
    const int k  = lane & 3;       // uint2 index 0..3 (feats 8k..8k+7)
    const int beg = rowptr[node], end = rowptr[node + 1];
    const int deg = end - beg;
    const int grpbase = threadIdx.x & 32;   // group offset within the 64-lane wave
    const int myc = (lane < deg) ? cols[beg + lane] : 0;
    const uint2* p64 = (const uint2*)p8;
    float a0 = 0.f, a1 = 0.f, a2 = 0.f, a3 = 0.f;
    float a4 = 0.f, a5 = 0.f, a6 = 0.f, a7 = 0.f;
#pragma unroll 2
    for (int base = 0; base < deg; base += 8) {
        const int idx = base + es;
        const bool valid = idx < deg;
        int s;
        if (idx < 32) s = __shfl(myc, grpbase + idx, 64);
        else          s = cols[beg + (valid ? idx : deg - 1)];
        const float scl = valid ? pscale[s] : 0.f;
        const uint2 w = p64[(size_t)s * 4 + k];
        a0 = fmaf((float)(signed char)(w.x & 0xffu), scl, a0);
        a1 = fmaf((float)(signed char)((w.x >> 8) & 0xffu), scl, a1);
        a2 = fmaf((float)(signed char)((w.x >> 16) & 0xffu), scl, a2);
        a3 = fmaf((float)(signed char)(w.x >> 24), scl, a3);
        a4 = fmaf((float)(signed char)(w.y & 0xffu), scl, a4);
        a5 = fmaf((float)(signed char)((w.y >> 8) & 0xffu), scl, a5);
        a6 = fmaf((float)(signed char)((w.y >> 16) & 0xffu), scl, a6);
        a7 = fmaf((float)(signed char)(w.y >> 24), scl, a7);
    }
#pragma unroll
    for (int d = 4; d <= 16; d <<= 1) {
        a0 += __shfl_xor(a0, d, 64); a1 += __shfl_xor(a1, d, 64);
        a2 += __shfl_xor(a2, d, 64); a3 += __shfl_xor(a3, d, 64);
        a4 += __shfl_xor(a4, d, 64); a5 += __shfl_xor(a5, d, 64);
        a6 += __shfl_xor(a6, d, 64); a7 += __shfl_xor(a7, d, 64);
    }
    if (es == 0) {
        const float dg = (float)deg;
        const float inv = 1.0f / fmaxf(dg, 1.0f);
        const uint4 qw = *(const uint4*)(qh + (size_t)node * 32 + 8 * k);
        const float2 q0 = unpackh2(qw.x), q1 = unpackh2(qw.y);
        const float2 q2 = unpackh2(qw.z), q3 = unpackh2(qw.w);
        const float4 cb0 = *(const float4*)(cbuf + 8 * k);
        const float4 cb1 = *(const float4*)(cbuf + 8 * k + 4);
        const float v0 = fmaf(a0, inv, q0.x + cb0.x);
        const float v1 = fmaf(a1, inv, q0.y + cb0.y);
        const float v2 = fmaf(a2, inv, q1.x + cb0.z);
        const float v3 = fmaf(a3, inv, q1.y + cb0.w);
        const float v4 = fmaf(a4, inv, q2.x + cb1.x);
        const float v5 = fmaf(a5, inv, q2.y + cb1.y);
        const float v6 = fmaf(a6, inv, q3.x + cb1.z);
        const float v7 = fmaf(a7, inv, q3.y + cb1.w);
        uint4 ow;
        ow.x = __builtin_bit_cast(unsigned, __floats2half2_rn(v0, v1));
        ow.y = __builtin_bit_cast(unsigned, __floats2half2_rn(v2, v3));
        ow.z = __builtin_bit_cast(unsigned, __floats2half2_rn(v4, v5));
        ow.w = __builtin_bit_cast(unsigned, __floats2half2_rn(v6, v7));
        if (k < 2) *(uint4*)(g + (size_t)node * 16 + 8 * k) = ow;
        else       *(uint4*)(r + (size_t)node * 16 + 8 * (k - 2)) = ow;
    }
}

__global__ __launch_bounds__(256) void agg2_csr(const int* __restrict__ rowptr,
    const int* __restrict__ cols, const __half* __restrict__ g,
    const __half* __restrict__ r, const float* __restrict__ b2,
    __half* __restrict__ h2)
{
    const int node = blockIdx.x * 8 + (threadIdx.x >> 5);
    if (node >= NN) return;
    const int lane = threadIdx.x & 31;
    const int es = lane >> 2;
    const int k  = lane & 3;       // feats 4k..4k+3
    const int beg = rowptr[node], end = rowptr[node + 1];
    const int deg = end - beg;
    const int grpbase = threadIdx.x & 32;
    const int myc = (lane < deg) ? cols[beg + lane] : 0;
    const uint2* g64 = (const uint2*)g;
    float a0 = 0.f, a1 = 0.f, a2 = 0.f, a3 = 0.f;
#pragma unroll 2
    for (int base = 0; base < deg; base += 8) {
        const int idx = base + es;
        const bool valid = idx < deg;
        int s;
        if (idx < 32) s = __shfl(myc, grpbase + idx, 64);
        else          s = cols[beg + (valid ? idx : deg - 1)];
        const float m = valid ? 1.0f : 0.0f;
        const uint2 w = g64[(size_t)s * 4 + k];
        const float2 v0 = unpackh2(w.x);
        const float2 v1 = unpackh2(w.y);
        a0 = fmaf(v0.x, m, a0);
        a1 = fmaf(v0.y, m, a1);
        a2 = fmaf(v1.x, m, a2);
        a3 = fmaf(v1.y, m, a3);
    }
#pragma unroll
    for (int d = 4; d <= 16; d <<= 1) {
        a0 += __shfl_xor(a0, d, 64); a1 += __shfl_xor(a1, d, 64);
        a2 += __shfl_xor(a2, d, 64); a3 += __shfl_xor(a3, d, 64);
    }
    if (es == 0) {
        const float dg = (float)deg;
        const float inv = 1.0f / fmaxf(dg, 1.0f);
        const uint2 rw = ((const uint2*)r)[(size_t)node * 4 + k];
        const float2 r0 = unpackh2(rw.x), r1 = unpackh2(rw.y);
        const float4 bb = *(const float4*)(b2 + 4 * k);
        const float v0 = fmaf(a0, inv, r0.x + bb.x);
        const float v1 = fmaf(a1, inv, r0.y + bb.y);
        const float v2 = fmaf(a2, inv, r1.x + bb.z);
        const float v3 = fmaf(a3, inv, r1.y + bb.w);
        uint2 ow;
        ow.x = __builtin_bit_cast(unsigned, __floats2half2_rn(v0, v1));
        ow.y = __builtin_bit_cast(unsigned, __floats2half2_rn(v2, v3));
        ((uint2*)h2)[(size_t)node * 4 + k] = ow;
    }
}

// ---- out = sigmoid( sum_k h2[s][k]*h2[d][k]*v[k] + c ); 4 edges per thread
__global__ __launch_bounds__(256) void edge_mlp(const int* __restrict__ src,
    const int* __restrict__ dst, const __half* __restrict__ h2,
    const float* __restrict__ cbuf, float* __restrict__ out)
{
    __shared__ float sv[17];
    if (threadIdx.x < 16) sv[threadIdx.x] = cbuf[32 + threadIdx.x];
    if (threadIdx.x == 16) sv[16] = cbuf[48];
    __syncthreads();
    const int ebase = blockIdx.x * 1024 + threadIdx.x;
#pragma unroll
    for (int u = 0; u < 4; ++u) {
        const int e = ebase + u * 256;
        if (e >= NE) return;
        const int s = src[e], d = dst[e];
        const uint4* hs = (const uint4*)(h2 + (size_t)s * 16);
        const uint4* hd = (const uint4*)(h2 + (size_t)d * 16);
        const uint4 a0 = hs[0], a1 = hs[1];
        const uint4 b0 = hd[0], b1 = hd[1];
        const unsigned aw[8] = {a0.x, a0.y, a0.z, a0.w, a1.x, a1.y, a1.z, a1.w};
        const unsigned bw[8] = {b0.x, b0.y, b0.z, b0.w, b1.x, b1.y, b1.z, b1.w};
        float acc = sv[16];
#pragma unroll
        for (int qq = 0; qq < 8; ++qq) {
            const float2 a = unpackh2(aw[qq]);
            const float2 b = unpackh2(bw[qq]);
            acc = fmaf(a.x * b.x, sv[qq * 2 + 0], acc);
            acc = fmaf(a.y * b.y, sv[qq * 2 + 1], acc);
        }
        out[e] = 1.0f / (1.0f + __expf(-acc));
    }
}

extern "C" void kernel_launch(void* const* d_in, const int* in_sizes, int n_in,
                              void* d_out, int out_size, void* d_ws, size_t ws_size,
                              hipStream_t stream)
{
    const float* x    = (const float*)d_in[0];
    const int*   ei   = (const int*)d_in[1];
    const float* w1l  = (const float*)d_in[2];
    const float* w1r  = (const float*)d_in[3];
    const float* b1   = (const float*)d_in[4];
    const float* w2l  = (const float*)d_in[5];
    const float* w2r  = (const float*)d_in[6];
    const float* b2   = (const float*)d_in[7];
    const float* fc1w = (const float*)d_in[8];
    const float* fc1b = (const float*)d_in[9];
    const float* fc2w = (const float*)d_in[10];
    const float* fc2b = (const float*)d_in[11];
    float* out = (float*)d_out;

    const int* src = ei;
    const int* dst = ei + NE;

    // workspace layout (int units)
    int* W = (int*)d_ws;
    size_t o = 0;
#define ALIGN16() o = (o + 15) & ~(size_t)15
    int* mat    = W + o; o += (size_t)NB * ABLK; ALIGN16();
    int* bbase  = W + o; o += NB + 1;            ALIGN16();
    int* rowptr = W + o; o += NN + 1;            ALIGN16();
    unsigned* part = (unsigned*)(W + o); o += NE; ALIGN16();
    int* cols   = W + o; o += NE;                ALIGN16();
    unsigned short* ATh = (unsigned short*)(W + o); o += 4096; ALIGN16();
    unsigned short* ATl = (unsigned short*)(W + o); o += 4096; ALIGN16();
    float* cbuf = (float*)(W + o); o += 64;      ALIGN16();
    signed char* p8 = (signed char*)(W + o); o += (size_t)NN * 8;  ALIGN16();
    float* pscale   = (float*)(W + o); o += NN;  ALIGN16();
    __half* qh  = (__half*)(W + o); o += (size_t)NN * 16; ALIGN16();
    __half* g   = (__half*)(W + o); o += (size_t)NN * 8;  ALIGN16();
    __half* r   = (__half*)(W + o); o += (size_t)NN * 8;  ALIGN16();
    __half* h2  = (__half*)(W + o); o += (size_t)NN * 8;  ALIGN16();

    // K1: count || precomp
    fused0<<<ABLK + 129, 256, 0, stream>>>(dst, w1l, w1r, w2l, w2r, b1,
                                           fc1w, fc1b, fc2w, fc2b, mat, ATh, ATl, cbuf);
    // K2: scatter(+inline scan) || gemm
    fused1<<<ABLK + GBLK, 512, 0, stream>>>(src, dst, mat, bbase, part,
                                            x, ATh, ATl, p8, pscale, qh);
    // K3: per-bucket CSR (391 blocks)
    partB_build<<<NB, 512, 0, stream>>>(part, bbase, rowptr, cols);
    // K4/K5: aggregations
    agg1_csr<<<(NN + 7) / 8, 256, 0, stream>>>(rowptr, cols, p8, pscale, qh, cbuf, g, r);
    agg2_csr<<<(NN + 7) / 8, 256, 0, stream>>>(rowptr, cols, g, r, b2, h2);
    // K6: head (4 edges/thread)
    edge_mlp<<<(NE + 1023) / 1024, 256, 0, stream>>>(src, dst, h2, cbuf, out);
}

// Round 23
// 120.534 us; speedup vs baseline: 1.2949x; 1.0133x over previous
//
#include <hip/hip_runtime.h>
#include <hip/hip_fp16.h>
#include <math.h>

#define NN 100000
#define NE 1600000

#define BSH  9          // bucket = dst >> 9
#define BKN  512        // nodes per bucket
#define NB   196        // ceil(NN/512)
#define ABLK 256        // partition blocks (EPB/NB ~ 32-entry runs = 128B, WC-safe)
#define EPB  ((NE + ABLK - 1) / ABLK)   // 6250 edges per partition block
#define GEMMB ((NN + 63) / 64)          // 1563 gemm tiles
#define GBLK ((GEMMB + 1) / 2)          // 782 gemm blocks (2 tiles each)
#define LDST 136

typedef __attribute__((ext_vector_type(8))) short bf16x8;
typedef __attribute__((ext_vector_type(4))) float f32x4;

__device__ __forceinline__ unsigned short f2bf(float f) {
    unsigned u = __builtin_bit_cast(unsigned, f);
    u += 0x7fffu + ((u >> 16) & 1u);           // RNE
    return (unsigned short)(u >> 16);
}
__device__ __forceinline__ float bf2f(unsigned short h) {
    unsigned u = ((unsigned)h) << 16;
    return __builtin_bit_cast(float, u);
}
__device__ __forceinline__ float2 unpackh2(unsigned w) {
    const __half2 h = __builtin_bit_cast(__half2, w);
    return __half22float2(h);
}

struct GemmSmem { unsigned short sAh[64 * LDST]; unsigned short sAl[64 * LDST]; };
struct ScatSmem { int cur[NB]; int tot[NB]; int sarr[512]; };
union F1Smem { GemmSmem gm; ScatSmem sc; };

// ============ K1: fused count (blocks 0..255) + precomp (256..384) ============
__global__ __launch_bounds__(256) void fused0(const int* __restrict__ dst,
    const float* __restrict__ w1l, const float* __restrict__ w1r,
    const float* __restrict__ w2l, const float* __restrict__ w2r,
    const float* __restrict__ b1, const float* __restrict__ fc1w,
    const float* __restrict__ fc1b, const float* __restrict__ fc2w,
    const float* __restrict__ fc2b, int* __restrict__ mat,
    unsigned short* __restrict__ ATh, unsigned short* __restrict__ ATl,
    float* __restrict__ cbuf)
{
    __shared__ int h[NB];
    __shared__ float sl[64], sr[64];
    const int t = threadIdx.x;
    if (blockIdx.x < ABLK) {
        for (int i = t; i < NB; i += 256) h[i] = 0;
        __syncthreads();
        const int a = blockIdx.x;
        const int beg = a * EPB;
        const int end = (beg + EPB < NE) ? beg + EPB : NE;
        int e = beg + t;
        for (; e + 3 * 256 < end; e += 4 * 256) {
            const int d0 = dst[e], d1 = dst[e + 256], d2 = dst[e + 512], d3 = dst[e + 768];
            atomicAdd(&h[d0 >> BSH], 1);
            atomicAdd(&h[d1 >> BSH], 1);
            atomicAdd(&h[d2 >> BSH], 1);
            atomicAdd(&h[d3 >> BSH], 1);
        }
        for (; e < end; e += 256)
            atomicAdd(&h[dst[e] >> BSH], 1);
        __syncthreads();
        for (int i = t; i < NB; i += 256) mat[(size_t)i * ABLK + a] = h[i];
        return;
    }
    if (blockIdx.x < ABLK + 128) {
        const int k = blockIdx.x - ABLK;
        const int j = t;
        if (j < 64) { sl[j] = w1l[k * 64 + j]; sr[j] = w1r[k * 64 + j]; }
        __syncthreads();
        if (j < 64) {
            const int sel = j >> 4, jj = j & 15;
            const float* row = (sel < 2) ? sl : sr;
            const float* w2  = (sel & 1) ? w2r : w2l;
            float acc = 0.f;
#pragma unroll
            for (int m = 0; m < 64; ++m) acc = fmaf(row[m], w2[m * 16 + jj], acc);
            const unsigned short hh = f2bf(acc);
            ATh[j * 128 + k] = hh;                  // transposed: [col][k]
            ATl[j * 128 + k] = f2bf(acc - bf2f(hh));
        }
        return;
    }
    const int j = t;
    if (j < 16) {
        float a = 0.f;
        for (int m = 0; m < 64; ++m) a = fmaf(b1[m], w2l[m * 16 + j], a);
        cbuf[j] = a;
    } else if (j < 32) {
        const int jj = j - 16;
        float a = 0.f;
        for (int m = 0; m < 64; ++m) a = fmaf(b1[m], w2r[m * 16 + jj], a);
        cbuf[j] = a;
    } else if (j < 48) {
        const int k = j - 32;
        float a = 0.f;
        for (int m = 0; m < 8; ++m) a = fmaf(fc1w[k * 8 + m], fc2w[m], a);
        cbuf[j] = a;
    } else if (j == 48) {
        float a = fc2b[0];
        for (int m = 0; m < 8; ++m) a = fmaf(fc1b[m], fc2w[m], a);
        cbuf[48] = a;
    }
}

// ============ K2: fused scatter+inline-scan (blocks 0..255) + gemm (256..) ======
__global__ __launch_bounds__(512) void fused1(const int* __restrict__ src,
    const int* __restrict__ dst, const int* __restrict__ mat,
    int* __restrict__ bbase, unsigned* __restrict__ part,
    const float* __restrict__ x, const unsigned short* __restrict__ ATh,
    const unsigned short* __restrict__ ATl, signed char* __restrict__ p8,
    float* __restrict__ pscale, __half* __restrict__ qh)
{
    __shared__ F1Smem su;
    const int tid = threadIdx.x;

    if (blockIdx.x < ABLK) {
        int* cur  = su.sc.cur;
        int* tot  = su.sc.tot;
        int* sarr = su.sc.sarr;
        // ---- inline scan: bucket totals + our block's within-bucket prefix ----
        const int a = blockIdx.x;
        for (int i = tid; i < NB; i += 512) {
            const int* col = mat + (size_t)i * ABLK;
            int run = 0, mypre = 0;
            for (int a2 = 0; a2 < ABLK; ++a2) {
                const int v = col[a2];
                mypre += (a2 < a) ? v : 0;
                run += v;
            }
            tot[i] = run;
            cur[i] = mypre;
        }
        __syncthreads();
        const int myrun = (tid < NB) ? tot[tid] : 0;
        sarr[tid] = myrun;
        __syncthreads();
        for (int off = 1; off < 512; off <<= 1) {
            const int u = (tid >= off) ? sarr[tid - off] : 0;
            __syncthreads();
            sarr[tid] += u;
            __syncthreads();
        }
        if (tid < NB) {
            const int base = sarr[tid] - myrun;   // exclusive bucket base
            cur[tid] += base;
            if (a == 0) bbase[tid] = base;        // persist for partB
        }
        if (a == 0 && tid == NB - 1) bbase[NB] = sarr[tid];
        __syncthreads();

        // ---- scatter (4x unrolled) ----
        const int beg = a * EPB;
        const int end = (beg + EPB < NE) ? beg + EPB : NE;
        int e = beg + tid;
        for (; e + 3 * 512 < end; e += 4 * 512) {
            const int s0 = src[e],          d0 = dst[e];
            const int s1 = src[e + 512],    d1 = dst[e + 512];
            const int s2 = src[e + 1024],   d2 = dst[e + 1024];
            const int s3 = src[e + 1536],   d3 = dst[e + 1536];
            const int p0 = atomicAdd(&cur[d0 >> BSH], 1);
            const int p1 = atomicAdd(&cur[d1 >> BSH], 1);
            const int p2 = atomicAdd(&cur[d2 >> BSH], 1);
            const int p3 = atomicAdd(&cur[d3 >> BSH], 1);
            part[p0] = ((unsigned)s0 << BSH) | (unsigned)(d0 & (BKN - 1));
            part[p1] = ((unsigned)s1 << BSH) | (unsigned)(d1 & (BKN - 1));
            part[p2] = ((unsigned)s2 << BSH) | (unsigned)(d2 & (BKN - 1));
            part[p3] = ((unsigned)s3 << BSH) | (unsigned)(d3 & (BKN - 1));
        }
        for (; e < end; e += 512) {
            const int s = src[e], d = dst[e];
            const int pos = atomicAdd(&cur[d >> BSH], 1);
            part[pos] = ((unsigned)s << BSH) | (unsigned)(d & (BKN - 1));
        }
        return;
    }

    // ---- gemm: 2 tiles per block, shared A staging ----
    unsigned short* sAh = su.gm.sAh;
    unsigned short* sAl = su.gm.sAl;
    for (int i = tid; i < 1024; i += 512) {
        const int row = i >> 4, ch = i & 15;
        const uint4 vh = *(const uint4*)(ATh + row * 128 + ch * 8);
        const uint4 vl = *(const uint4*)(ATl + row * 128 + ch * 8);
        *(uint4*)(sAh + row * LDST + ch * 8) = vh;
        *(uint4*)(sAl + row * LDST + ch * 8) = vl;
    }
    __syncthreads();

    const int wave8 = tid >> 6;            // 0..7
    const int tile = (blockIdx.x - ABLK) * 2 + (wave8 >> 2);
    const int wave = wave8 & 3;            // 0..3 within tile-group
    const int lane = tid & 63;
    const int lr = lane & 15;
    const int lg = lane >> 4;

    bf16x8 bh[4][4], bl[4][4];
#pragma unroll
    for (int ct = 0; ct < 4; ++ct) {
        const int col = ct * 16 + lr;
#pragma unroll
        for (int ks = 0; ks < 4; ++ks) {
            const int k0 = ks * 32 + lg * 8;
            bh[ct][ks] = *(const bf16x8*)(sAh + col * LDST + k0);
            bl[ct][ks] = *(const bf16x8*)(sAl + col * LDST + k0);
        }
    }

    if (tile >= GEMMB) return;
    const int tilebase = tile * 64;
    const int xrowidx = tilebase + wave * 16 + lr;
    const float* xrow = x + (size_t)(xrowidx < NN ? xrowidx : NN - 1) * 128;

    f32x4 acc[4] = {f32x4{0,0,0,0}, f32x4{0,0,0,0}, f32x4{0,0,0,0}, f32x4{0,0,0,0}};
#pragma unroll
    for (int ks = 0; ks < 4; ++ks) {
        const int k0 = ks * 32 + lg * 8;
        const float4 v0 = *(const float4*)(xrow + k0);
        const float4 v1 = *(const float4*)(xrow + k0 + 4);
        const float vv[8] = {v0.x, v0.y, v0.z, v0.w, v1.x, v1.y, v1.z, v1.w};
        bf16x8 xh, xl;
#pragma unroll
        for (int j = 0; j < 8; ++j) {
            const unsigned short h = f2bf(vv[j]);
            xh[j] = (short)h;
            xl[j] = (short)f2bf(vv[j] - bf2f(h));
        }
#pragma unroll
        for (int ct = 0; ct < 4; ++ct) {
            acc[ct] = __builtin_amdgcn_mfma_f32_16x16x32_bf16(xh, bh[ct][ks], acc[ct], 0, 0, 0);
            acc[ct] = __builtin_amdgcn_mfma_f32_16x16x32_bf16(xh, bl[ct][ks], acc[ct], 0, 0, 0);
            acc[ct] = __builtin_amdgcn_mfma_f32_16x16x32_bf16(xl, bh[ct][ks], acc[ct], 0, 0, 0);
        }
    }

#pragma unroll
    for (int rg = 0; rg < 4; ++rg) {
        float m = fmaxf(fabsf(acc[0][rg]), fabsf(acc[1][rg]));
#pragma unroll
        for (int d = 1; d < 16; d <<= 1) m = fmaxf(m, __shfl_xor(m, d, 64));
        m = fmaxf(m, 1e-20f);
        const float scl = m * (1.0f / 127.0f);
        const float inv = 127.0f / m;
        const int nrow = tilebase + wave * 16 + lg * 4 + rg;
        if (nrow < NN) {
            const int q0 = __float2int_rn(acc[0][rg] * inv);
            const int q1 = __float2int_rn(acc[1][rg] * inv);
            p8[(size_t)nrow * 32 + lr]      = (signed char)q0;
            p8[(size_t)nrow * 32 + 16 + lr] = (signed char)q1;
            if (lr == 0) pscale[nrow] = scl;
            qh[(size_t)nrow * 32 + lr]      = __float2half(acc[2][rg]);
            qh[(size_t)nrow * 32 + 16 + lr] = __float2half(acc[3][rg]);
        }
    }
}

// ============ K3: per-bucket CSR build (196 blocks, BKN=512) ============
__global__ __launch_bounds__(512) void partB_build(const unsigned* __restrict__ part,
    const int* __restrict__ bbase, int* __restrict__ rowptr, int* __restrict__ cols)
{
    __shared__ int h[BKN];
    __shared__ int cur[BKN];
    __shared__ int wsum[8];
    const int b = blockIdx.x;
    const int t = threadIdx.x;
    const int beg = bbase[b], end = bbase[b + 1];
    h[t] = 0;
    __syncthreads();
    {
        int e = beg + t;
        for (; e + 3 * 512 < end; e += 4 * 512) {
            const unsigned w0 = part[e], w1 = part[e + 512];
            const unsigned w2 = part[e + 1024], w3 = part[e + 1536];
            atomicAdd(&h[w0 & (BKN - 1u)], 1);
            atomicAdd(&h[w1 & (BKN - 1u)], 1);
            atomicAdd(&h[w2 & (BKN - 1u)], 1);
            atomicAdd(&h[w3 & (BKN - 1u)], 1);
        }
        for (; e < end; e += 512)
            atomicAdd(&h[part[e] & (BKN - 1u)], 1);
    }
    __syncthreads();
    const int v = h[t];
    int inc = v;
#pragma unroll
    for (int d = 1; d < 64; d <<= 1) {
        const int u = __shfl_up(inc, d, 64);
        if ((t & 63) >= d) inc += u;
    }
    if ((t & 63) == 63) wsum[t >> 6] = inc;
    __syncthreads();
    int woff = 0;
    for (int w = 0; w < (t >> 6); ++w) woff += wsum[w];
    const int excl = inc + woff - v;
    cur[t] = excl;
    const int node = b * BKN + t;
    if (node < NN) rowptr[node] = beg + excl;
    if (b == NB - 1 && t == 0) rowptr[NN] = NE;
    __syncthreads();
    {
        int e = beg + t;
        for (; e + 3 * 512 < end; e += 4 * 512) {
            const unsigned w0 = part[e], w1 = part[e + 512];
            const unsigned w2 = part[e + 1024], w3 = part[e + 1536];
            const int p0 = atomicAdd(&cur[w0 & (BKN - 1u)], 1);
            const int p1 = atomicAdd(&cur[w1 & (BKN - 1u)], 1);
            const int p2 = atomicAdd(&cur[w2 & (BKN - 1u)], 1);
            const int p3 = atomicAdd(&cur[w3 & (BKN - 1u)], 1);
            cols[beg + p0] = (int)(w0 >> BSH);
            cols[beg + p1] = (int)(w1 >> BSH);
            cols[beg + p2] = (int)(w2 >> BSH);
            cols[beg + p3] = (int)(w3 >> BSH);
        }
        for (; e < end; e += 512) {
            const unsigned w = part[e];
            const int pos = atomicAdd(&cur[w & (BKN - 1u)], 1);
            cols[beg + pos] = (int)(w >> BSH);
        }
    }
}

// ============ aggregation via CSR: register-cached cols + shfl ============
__global__ __launch_bounds__(256) void agg1_csr(const int* __restrict__ rowptr,
    const int* __restrict__ cols, const signed char* __restrict__ p8,
    const float* __restrict__ pscale, const __half* __restrict__ qh,
    const float* __restrict__ cbuf, __half* __restrict__ g, __half* __restrict__ r)
{
    const int node = blockIdx.x * 8 + (threadIdx.x >> 5);
    if (node >= NN) return;
    const int lane = threadIdx.x & 31;
    const int es = lane >> 2;      // edge slot 0..7
    const int k  = lane & 3;       // uint2 index 0..3 (feats 8k..8k+7)
    const int beg = rowptr[node], end = rowptr[node + 1];
    const int deg = end - beg;
    const int grpbase = threadIdx.x & 32;   // group offset within the 64-lane wave
    const int myc = (lane < deg) ? cols[beg + lane] : 0;
    const uint2* p64 = (const uint2*)p8;
    float a0 = 0.f, a1 = 0.f, a2 = 0.f, a3 = 0.f;
    float a4 = 0.f, a5 = 0.f, a6 = 0.f, a7 = 0.f;
#pragma unroll 2
    for (int base = 0; base < deg; base += 8) {
        const int idx = base + es;
        const bool valid = idx < deg;
        int s;
        if (idx < 32) s = __shfl(myc, grpbase + idx, 64);
        else          s = cols[beg + (valid ? idx : deg - 1)];
        const float scl = valid ? pscale[s] : 0.f;
        const uint2 w = p64[(size_t)s * 4 + k];
        a0 = fmaf((float)(signed char)(w.x & 0xffu), scl, a0);
        a1 = fmaf((float)(signed char)((w.x >> 8) & 0xffu), scl, a1);
        a2 = fmaf((float)(signed char)((w.x >> 16) & 0xffu), scl, a2);
        a3 = fmaf((float)(signed char)(w.x >> 24), scl, a3);
        a4 = fmaf((float)(signed char)(w.y & 0xffu), scl, a4);
        a5 = fmaf((float)(signed char)((w.y >> 8) & 0xffu), scl, a5);
        a6 = fmaf((float)(signed char)((w.y >> 16) & 0xffu), scl, a6);
        a7 = fmaf((float)(signed char)(w.y >> 24), scl, a7);
    }
#pragma unroll
    for (int d = 4; d <= 16; d <<= 1) {
        a0 += __shfl_xor(a0, d, 64); a1 += __shfl_xor(a1, d, 64);
        a2 += __shfl_xor(a2, d, 64); a3 += __shfl_xor(a3, d, 64);
        a4 += __shfl_xor(a4, d, 64); a5 += __shfl_xor(a5, d, 64);
        a6 += __shfl_xor(a6, d, 64); a7 += __shfl_xor(a7, d, 64);
    }
    if (es == 0) {
        const float dg = (float)deg;
        const float inv = 1.0f / fmaxf(dg, 1.0f);
        const uint4 qw = *(const uint4*)(qh + (size_t)node * 32 + 8 * k);
        const float2 q0 = unpackh2(qw.x), q1 = unpackh2(qw.y);
        const float2 q2 = unpackh2(qw.z), q3 = unpackh2(qw.w);
        const float4 cb0 = *(const float4*)(cbuf + 8 * k);
        const float4 cb1 = *(const float4*)(cbuf + 8 * k + 4);
        const float v0 = fmaf(a0, inv, q0.x + cb0.x);
        const float v1 = fmaf(a1, inv, q0.y + cb0.y);
        const float v2 = fmaf(a2, inv, q1.x + cb0.z);
        const float v3 = fmaf(a3, inv, q1.y + cb0.w);
        const float v4 = fmaf(a4, inv, q2.x + cb1.x);
        const float v5 = fmaf(a5, inv, q2.y + cb1.y);
        const float v6 = fmaf(a6, inv, q3.x + cb1.z);
        const float v7 = fmaf(a7, inv, q3.y + cb1.w);
        uint4 ow;
        ow.x = __builtin_bit_cast(unsigned, __floats2half2_rn(v0, v1));
        ow.y = __builtin_bit_cast(unsigned, __floats2half2_rn(v2, v3));
        ow.z = __builtin_bit_cast(unsigned, __floats2half2_rn(v4, v5));
        ow.w = __builtin_bit_cast(unsigned, __floats2half2_rn(v6, v7));
        if (k < 2) *(uint4*)(g + (size_t)node * 16 + 8 * k) = ow;
        else       *(uint4*)(r + (size_t)node * 16 + 8 * (k - 2)) = ow;
    }
}

__global__ __launch_bounds__(256) void agg2_csr(const int* __restrict__ rowptr,
    const int* __restrict__ cols, const __half* __restrict__ g,
    const __half* __restrict__ r, const float* __restrict__ b2,
    __half* __restrict__ h2)
{
    const int node = blockIdx.x * 8 + (threadIdx.x >> 5);
    if (node >= NN) return;
    const int lane = threadIdx.x & 31;
    const int es = lane >> 2;
    const int k  = lane & 3;       // feats 4k..4k+3
    const int beg = rowptr[node], end = rowptr[node + 1];
    const int deg = end - beg;
    const int grpbase = threadIdx.x & 32;
    const int myc = (lane < deg) ? cols[beg + lane] : 0;
    const uint2* g64 = (const uint2*)g;
    float a0 = 0.f, a1 = 0.f, a2 = 0.f, a3 = 0.f;
#pragma unroll 2
    for (int base = 0; base < deg; base += 8) {
        const int idx = base + es;
        const bool valid = idx < deg;
        int s;
        if (idx < 32) s = __shfl(myc, grpbase + idx, 64);
        else          s = cols[beg + (valid ? idx : deg - 1)];
        const float m = valid ? 1.0f : 0.0f;
        const uint2 w = g64[(size_t)s * 4 + k];
        const float2 v0 = unpackh2(w.x);
        const float2 v1 = unpackh2(w.y);
        a0 = fmaf(v0.x, m, a0);
        a1 = fmaf(v0.y, m, a1);
        a2 = fmaf(v1.x, m, a2);
        a3 = fmaf(v1.y, m, a3);
    }
#pragma unroll
    for (int d = 4; d <= 16; d <<= 1) {
        a0 += __shfl_xor(a0, d, 64); a1 += __shfl_xor(a1, d, 64);
        a2 += __shfl_xor(a2, d, 64); a3 += __shfl_xor(a3, d, 64);
    }
    if (es == 0) {
        const float dg = (float)deg;
        const float inv = 1.0f / fmaxf(dg, 1.0f);
        const uint2 rw = ((const uint2*)r)[(size_t)node * 4 + k];
        const float2 r0 = unpackh2(rw.x), r1 = unpackh2(rw.y);
        const float4 bb = *(const float4*)(b2 + 4 * k);
        const float v0 = fmaf(a0, inv, r0.x + bb.x);
        const float v1 = fmaf(a1, inv, r0.y + bb.y);
        const float v2 = fmaf(a2, inv, r1.x + bb.z);
        const float v3 = fmaf(a3, inv, r1.y + bb.w);
        uint2 ow;
        ow.x = __builtin_bit_cast(unsigned, __floats2half2_rn(v0, v1));
        ow.y = __builtin_bit_cast(unsigned, __floats2half2_rn(v2, v3));
        ((uint2*)h2)[(size_t)node * 4 + k] = ow;
    }
}

// ---- out = sigmoid( sum_k h2[s][k]*h2[d][k]*v[k] + c ); 4 edges per thread
__global__ __launch_bounds__(256) void edge_mlp(const int* __restrict__ src,
    const int* __restrict__ dst, const __half* __restrict__ h2,
    const float* __restrict__ cbuf, float* __restrict__ out)
{
    __shared__ float sv[17];
    if (threadIdx.x < 16) sv[threadIdx.x] = cbuf[32 + threadIdx.x];
    if (threadIdx.x == 16) sv[16] = cbuf[48];
    __syncthreads();
    const int ebase = blockIdx.x * 1024 + threadIdx.x;
#pragma unroll
    for (int u = 0; u < 4; ++u) {
        const int e = ebase + u * 256;
        if (e >= NE) return;
        const int s = src[e], d = dst[e];
        const uint4* hs = (const uint4*)(h2 + (size_t)s * 16);
        const uint4* hd = (const uint4*)(h2 + (size_t)d * 16);
        const uint4 a0 = hs[0], a1 = hs[1];
        const uint4 b0 = hd[0], b1 = hd[1];
        const unsigned aw[8] = {a0.x, a0.y, a0.z, a0.w, a1.x, a1.y, a1.z, a1.w};
        const unsigned bw[8] = {b0.x, b0.y, b0.z, b0.w, b1.x, b1.y, b1.z, b1.w};
        float acc = sv[16];
#pragma unroll
        for (int qq = 0; qq < 8; ++qq) {
            const float2 a = unpackh2(aw[qq]);
            const float2 b = unpackh2(bw[qq]);
            acc = fmaf(a.x * b.x, sv[qq * 2 + 0], acc);
            acc = fmaf(a.y * b.y, sv[qq * 2 + 1], acc);
        }
        out[e] = 1.0f / (1.0f + __expf(-acc));
    }
}

extern "C" void kernel_launch(void* const* d_in, const int* in_sizes, int n_in,
                              void* d_out, int out_size, void* d_ws, size_t ws_size,
                              hipStream_t stream)
{
    const float* x    = (const float*)d_in[0];
    const int*   ei   = (const int*)d_in[1];
    const float* w1l  = (const float*)d_in[2];
    const float* w1r  = (const float*)d_in[3];
    const float* b1   = (const float*)d_in[4];
    const float* w2l  = (const float*)d_in[5];
    const float* w2r  = (const float*)d_in[6];
    const float* b2   = (const float*)d_in[7];
    const float* fc1w = (const float*)d_in[8];
    const float* fc1b = (const float*)d_in[9];
    const float* fc2w = (const float*)d_in[10];
    const float* fc2b = (const float*)d_in[11];
    float* out = (float*)d_out;

    const int* src = ei;
    const int* dst = ei + NE;

    // workspace layout (int units)
    int* W = (int*)d_ws;
    size_t o = 0;
#define ALIGN16() o = (o + 15) & ~(size_t)15
    int* mat    = W + o; o += (size_t)NB * ABLK; ALIGN16();
    int* bbase  = W + o; o += NB + 1;            ALIGN16();
    int* rowptr = W + o; o += NN + 1;            ALIGN16();
    unsigned* part = (unsigned*)(W + o); o += NE; ALIGN16();
    int* cols   = W + o; o += NE;                ALIGN16();
    unsigned short* ATh = (unsigned short*)(W + o); o += 4096; ALIGN16();
    unsigned short* ATl = (unsigned short*)(W + o); o += 4096; ALIGN16();
    float* cbuf = (float*)(W + o); o += 64;      ALIGN16();
    signed char* p8 = (signed char*)(W + o); o += (size_t)NN * 8;  ALIGN16();
    float* pscale   = (float*)(W + o); o += NN;  ALIGN16();
    __half* qh  = (__half*)(W + o); o += (size_t)NN * 16; ALIGN16();
    __half* g   = (__half*)(W + o); o += (size_t)NN * 8;  ALIGN16();
    __half* r   = (__half*)(W + o); o += (size_t)NN * 8;  ALIGN16();
    __half* h2  = (__half*)(W + o); o += (size_t)NN * 8;  ALIGN16();

    // K1: count || precomp
    fused0<<<ABLK + 129, 256, 0, stream>>>(dst, w1l, w1r, w2l, w2r, b1,
                                           fc1w, fc1b, fc2w, fc2b, mat, ATh, ATl, cbuf);
    // K2: scatter(+inline scan, 256 blocks) || gemm
    fused1<<<ABLK + GBLK, 512, 0, stream>>>(src, dst, mat, bbase, part,
                                            x, ATh, ATl, p8, pscale, qh);
    // K3: per-bucket CSR (196 blocks)
    partB_build<<<NB, 512, 0, stream>>>(part, bbase, rowptr, cols);
    // K4/K5: aggregations
    agg1_csr<<<(NN + 7) / 8, 256, 0, stream>>>(rowptr, cols, p8, pscale, qh, cbuf, g, r);
    agg2_csr<<<(NN + 7) / 8, 256, 0, stream>>>(rowptr, cols, g, r, b2, h2);
    // K6: head (4 edges/thread)
    edge_mlp<<<(NE + 1023) / 1024, 256, 0, stream>>>(src, dst, h2, cbuf, out);
}